// Round 1
// baseline (13430.025 us; speedup 1.0000x reference)
//
#include <hip/hip_runtime.h>
#include <hip/hip_bf16.h>
#include <cstddef>

#define BB 128  // batch

// ---------------- GEMM: C[M,N] = A[M,K] x B (TRANS_B: B[N,K] else B[K,N]), ACT=1 -> relu
template<int TRANS_B, int ACT>
__global__ __launch_bounds__(256) void gemm_kernel(
    const float* __restrict__ A, const float* __restrict__ Bm,
    float* __restrict__ C, int M, int N, int K, int lda, int ldb, int ldc)
{
    __shared__ float At[64][33];
    __shared__ float Bt[32][33];
    const int n0 = blockIdx.x * 32;
    const int m0 = blockIdx.y * 64;
    const int tid = threadIdx.x;
    const int n  = tid & 31;
    const int rg = tid >> 5;
    float acc[8];
    #pragma unroll
    for (int r = 0; r < 8; ++r) acc[r] = 0.f;

    for (int k0 = 0; k0 < K; k0 += 32) {
        #pragma unroll
        for (int u = 0; u < 2; ++u) {
            int f = tid + u * 256;
            int row = f >> 3;
            int c4 = (f & 7) << 2;
            float4 v = *(const float4*)(&A[(size_t)(m0 + row) * lda + k0 + c4]);
            At[row][c4 + 0] = v.x; At[row][c4 + 1] = v.y;
            At[row][c4 + 2] = v.z; At[row][c4 + 3] = v.w;
        }
        {
            int row = tid >> 3;
            int c4 = (tid & 7) << 2;
            if (TRANS_B) {
                float4 v = *(const float4*)(&Bm[(size_t)(n0 + row) * ldb + k0 + c4]);
                Bt[c4 + 0][row] = v.x; Bt[c4 + 1][row] = v.y;
                Bt[c4 + 2][row] = v.z; Bt[c4 + 3][row] = v.w;
            } else {
                float4 v = *(const float4*)(&Bm[(size_t)(k0 + row) * ldb + n0 + c4]);
                Bt[row][c4 + 0] = v.x; Bt[row][c4 + 1] = v.y;
                Bt[row][c4 + 2] = v.z; Bt[row][c4 + 3] = v.w;
            }
        }
        __syncthreads();
        #pragma unroll
        for (int kk = 0; kk < 32; ++kk) {
            float bv = Bt[kk][n];
            #pragma unroll
            for (int r = 0; r < 8; ++r)
                acc[r] += At[rg * 8 + r][kk] * bv;
        }
        __syncthreads();
    }
    #pragma unroll
    for (int r = 0; r < 8; ++r) {
        float v = acc[r];
        if (ACT == 1) v = fmaxf(v, 0.f);
        C[(size_t)(m0 + rg * 8 + r) * ldc + n0 + n] = v;
    }
}

// ---------------- copy image channels into x0 (channel 3 is written by FC GEMM)
__global__ __launch_bounds__(256) void pack_img(const float* __restrict__ img, float* __restrict__ x0)
{
    int idx = blockIdx.x * 256 + threadIdx.x;           // over 128*3*4096
    int s = idx & 4095;
    int rem = idx >> 12;
    int c = rem % 3;
    int b = rem / 3;
    x0[(size_t)b * 16384 + c * 4096 + s] = img[idx];
}

// ---------------- direct conv, 4x4 s2 p1, block = (b,oc), threads cover spatial
template<int IC, int IH, int OC, int ACT>   // ACT=1 lrelu, 0 none
__global__ __launch_bounds__(256) void conv_spatial(
    const float* __restrict__ x, const float* __restrict__ w, float* __restrict__ y)
{
    constexpr int IW = IH, OH = IH / 2, OW = IH / 2, S = OH * OW;
    __shared__ float wsm[IC * 16];
    const int oc = blockIdx.x % OC;
    const int b  = blockIdx.x / OC;
    for (int i = threadIdx.x; i < IC * 16; i += 256)
        wsm[i] = w[(size_t)oc * IC * 16 + i];
    __syncthreads();
    const float* xb = x + (size_t)b * IC * IH * IW;
    for (int s = threadIdx.x; s < S; s += 256) {
        const int oh = s / OW, ow = s % OW;
        float acc = 0.f;
        for (int ic = 0; ic < IC; ++ic) {
            const float* xp = xb + ic * IH * IW;
            const float* wp = wsm + ic * 16;
            #pragma unroll
            for (int kh = 0; kh < 4; ++kh) {
                int ih = oh * 2 - 1 + kh;
                if ((unsigned)ih >= (unsigned)IH) continue;
                #pragma unroll
                for (int kw = 0; kw < 4; ++kw) {
                    int iw = ow * 2 - 1 + kw;
                    if ((unsigned)iw >= (unsigned)IW) continue;
                    acc += xp[ih * IW + iw] * wp[kh * 4 + kw];
                }
            }
        }
        if (ACT == 1) acc = (acc >= 0.f) ? acc : 0.2f * acc;
        y[((size_t)b * OC + oc) * S + s] = acc;
    }
}

// ---------------- direct conv with K-split across threads (small spatial)
template<int IC, int IH, int OC, int SPLIT>
__global__ __launch_bounds__(256) void conv_ksplit(
    const float* __restrict__ x, const float* __restrict__ w, float* __restrict__ y)
{
    constexpr int IW = IH, OH = IH / 2, OW = IH / 2, S = OH * OW;
    constexpr int NT = S * SPLIT;          // == 256
    constexpr int ICPC = IC / SPLIT;
    __shared__ float wsm[IC * 16];
    __shared__ float red[NT];
    const int oc = blockIdx.x % OC;
    const int b  = blockIdx.x / OC;
    for (int i = threadIdx.x; i < IC * 16; i += NT)
        wsm[i] = w[(size_t)oc * IC * 16 + i];
    __syncthreads();
    const int tid = threadIdx.x;
    const int s = tid % S, ch = tid / S;
    const int oh = s / OW, ow = s % OW;
    const float* xb = x + (size_t)b * IC * IH * IW;
    float acc = 0.f;
    for (int ic = ch * ICPC; ic < (ch + 1) * ICPC; ++ic) {
        const float* xp = xb + ic * IH * IW;
        const float* wp = wsm + ic * 16;
        #pragma unroll
        for (int kh = 0; kh < 4; ++kh) {
            int ih = oh * 2 - 1 + kh;
            if ((unsigned)ih >= (unsigned)IH) continue;
            #pragma unroll
            for (int kw = 0; kw < 4; ++kw) {
                int iw = ow * 2 - 1 + kw;
                if ((unsigned)iw >= (unsigned)IW) continue;
                acc += xp[ih * IW + iw] * wp[kh * 4 + kw];
            }
        }
    }
    red[tid] = acc;
    __syncthreads();
    if (tid < S) {
        float t = red[tid];
        #pragma unroll
        for (int c2 = 1; c2 < SPLIT; ++c2) t += red[tid + c2 * S];
        y[((size_t)b * OC + oc) * S + tid] = t;
    }
}

// ---------------- BN: per-channel mean / rstd over (N,H,W)
__global__ __launch_bounds__(256) void bn_reduce(
    const float* __restrict__ x, float* __restrict__ mean, float* __restrict__ rstd,
    int C, int lhw)
{
    const int c = blockIdx.x;
    const int HWm = (1 << lhw) - 1;
    float s = 0.f, ss = 0.f;
    const int total = BB << lhw;
    for (int t = threadIdx.x; t < total; t += 256) {
        int b = t >> lhw;
        int i = t & HWm;
        float v = x[(((size_t)b * C + c) << lhw) + i];
        s += v; ss += v * v;
    }
    #pragma unroll
    for (int off = 32; off > 0; off >>= 1) {
        s  += __shfl_down(s, off);
        ss += __shfl_down(ss, off);
    }
    __shared__ float a1[4], a2[4];
    const int wid = threadIdx.x >> 6, lane = threadIdx.x & 63;
    if (lane == 0) { a1[wid] = s; a2[wid] = ss; }
    __syncthreads();
    if (threadIdx.x == 0) {
        s = a1[0] + a1[1] + a1[2] + a1[3];
        ss = a2[0] + a2[1] + a2[2] + a2[3];
        float cnt = (float)(BB << lhw);
        float m = s / cnt;
        float var = ss / cnt - m * m;
        mean[c] = m;
        rstd[c] = rsqrtf(var + 1e-5f);
    }
}

__global__ __launch_bounds__(256) void bn_apply_lrelu(
    float* __restrict__ x, const float* __restrict__ mean, const float* __restrict__ rstd,
    const float* __restrict__ g, const float* __restrict__ be, int cmask, int lhw)
{
    int idx = blockIdx.x * 256 + threadIdx.x;
    int c = (idx >> lhw) & cmask;
    float v = x[idx];
    v = (v - mean[c]) * rstd[c] * g[c] + be[c];
    x[idx] = (v >= 0.f) ? v : 0.2f * v;
}

// ---------------- conv5: [128,512,4,4] -> feat rows of d_out (stride 1280)
__global__ __launch_bounds__(256) void conv5_kernel(
    const float* __restrict__ x, const float* __restrict__ w, float* __restrict__ out)
{
    __shared__ float xs[8192];             // 512*16 floats = 32 KB
    const int b = blockIdx.x;
    const float* xb = x + (size_t)b * 8192;
    for (int i = threadIdx.x * 4; i < 8192; i += 1024)
        *(float4*)&xs[i] = *(const float4*)&xb[i];
    __syncthreads();
    const int oc = threadIdx.x;
    float acc0 = 0.f, acc1 = 0.f, acc2 = 0.f, acc3 = 0.f;
    const float* wp = w + (size_t)oc * 8192;
    for (int ic = 0; ic < 512; ++ic) {
        float wr[16];
        #pragma unroll
        for (int u = 0; u < 4; ++u) {
            float4 v = *(const float4*)&wp[ic * 16 + u * 4];
            wr[u * 4 + 0] = v.x; wr[u * 4 + 1] = v.y;
            wr[u * 4 + 2] = v.z; wr[u * 4 + 3] = v.w;
        }
        const float* xp = xs + ic * 16;
        #pragma unroll
        for (int oh = 0; oh < 2; ++oh) {
            #pragma unroll
            for (int ow = 0; ow < 2; ++ow) {
                float a = 0.f;
                #pragma unroll
                for (int kh = 0; kh < 4; ++kh) {
                    int ih = oh * 2 - 1 + kh;
                    if ((unsigned)ih >= 4u) continue;
                    #pragma unroll
                    for (int kw = 0; kw < 4; ++kw) {
                        int iw = ow * 2 - 1 + kw;
                        if ((unsigned)iw >= 4u) continue;
                        a += xp[ih * 4 + iw] * wr[kh * 4 + kw];
                    }
                }
                if (oh == 0 && ow == 0) acc0 += a;
                else if (oh == 0 && ow == 1) acc1 += a;
                else if (oh == 1 && ow == 0) acc2 += a;
                else acc3 += a;
            }
        }
    }
    float* op = out + (size_t)b * 1280 + oc * 4;
    op[0] = acc0; op[1] = acc1; op[2] = acc2; op[3] = acc3;
}

// ---------------- minibatch discrimination
__global__ __launch_bounds__(256) void mbd_kernel(
    const float* __restrict__ Ms, float* __restrict__ out)
{
    const int i = blockIdx.x;
    const int o = threadIdx.x;
    float mi[16];
    #pragma unroll
    for (int u = 0; u < 4; ++u) {
        float4 v = *(const float4*)&Ms[(size_t)i * 4096 + o * 16 + u * 4];
        mi[u * 4 + 0] = v.x; mi[u * 4 + 1] = v.y;
        mi[u * 4 + 2] = v.z; mi[u * 4 + 3] = v.w;
    }
    float acc = 0.f;
    for (int j = 0; j < BB; ++j) {
        float d = 0.f;
        #pragma unroll
        for (int u = 0; u < 4; ++u) {
            float4 v = *(const float4*)&Ms[(size_t)j * 4096 + o * 16 + u * 4];
            d += fabsf(mi[u * 4 + 0] - v.x);
            d += fabsf(mi[u * 4 + 1] - v.y);
            d += fabsf(mi[u * 4 + 2] - v.z);
            d += fabsf(mi[u * 4 + 3] - v.w);
        }
        acc += expf(-d);
    }
    out[(size_t)i * 1280 + 1024 + o] = acc;
}

__global__ void ws_too_small(float* out, int n)
{
    int idx = blockIdx.x * 256 + threadIdx.x;
    if (idx < n) out[idx] = -777.0f;
}

extern "C" void kernel_launch(void* const* d_in, const int* in_sizes, int n_in,
                              void* d_out, int out_size, void* d_ws, size_t ws_size,
                              hipStream_t stream)
{
    const float* image = (const float*)d_in[0];
    const float* wvec  = (const float*)d_in[1];
    const float* fc_w  = (const float*)d_in[2];
    const float* w1    = (const float*)d_in[3];
    const float* w2    = (const float*)d_in[4];
    const float* w3    = (const float*)d_in[5];
    const float* w4    = (const float*)d_in[6];
    const float* w5    = (const float*)d_in[7];
    const float* g2    = (const float*)d_in[8];
    const float* b2    = (const float*)d_in[9];
    const float* g3    = (const float*)d_in[10];
    const float* b3    = (const float*)d_in[11];
    const float* g4    = (const float*)d_in[12];
    const float* b4    = (const float*)d_in[13];
    const float* T     = (const float*)d_in[14];
    float* out = (float*)d_out;
    float* ws  = (float*)d_ws;

    // ws layout (floats), lifetime-packed:
    //   [0 .. 16777216)           x1  [128,128,32,32]   (dead after conv2)
    //   [16777216 .. 25165824)    x2  [128,256,16,16]
    //   [25165824 .. 27262976)    x0  [128,4,64,64]
    //   after conv2, inside old x1 region:
    //   [0 .. 2097152)            x3  [128,256,8,8]
    //   [2097152 .. 3145728)      x4  [128,512,4,4]
    //   [3145728 .. 3670016)      Ms  [128,4096]
    //   [3670016 .. 3671040)      mean/rstd (512 each)
    const size_t NEED = 27262976ull * 4ull;
    if (ws_size < NEED) {
        ws_too_small<<<(out_size + 255) / 256, 256, 0, stream>>>(out, out_size);
        return;
    }
    float* x1   = ws;
    float* x2   = ws + 16777216;
    float* x0   = ws + 25165824;
    float* x3   = ws;
    float* x4   = ws + 2097152;
    float* Ms   = ws + 3145728;
    float* mean = ws + 3670016;
    float* rstd = ws + 3670016 + 512;

    // 1. FC: wv = relu(word_vectors @ fc_w^T), written into x0 channel 3 (ldc=16384)
    gemm_kernel<1, 1><<<dim3(128, 2), 256, 0, stream>>>(
        wvec, fc_w, x0 + 3 * 4096, 128, 4096, 4096, 4096, 4096, 16384);
    // 2. image -> x0 channels 0..2
    pack_img<<<(BB * 3 * 4096) / 256, 256, 0, stream>>>(image, x0);
    // 3. conv1 + lrelu: [128,4,64,64] -> [128,128,32,32]
    conv_spatial<4, 64, 128, 1><<<BB * 128, 256, 0, stream>>>(x0, w1, x1);
    // 4. conv2: [128,128,32,32] -> [128,256,16,16]
    conv_spatial<128, 32, 256, 0><<<BB * 256, 256, 0, stream>>>(x1, w2, x2);
    // 5. BN2 + lrelu (in place)
    bn_reduce<<<256, 256, 0, stream>>>(x2, mean, rstd, 256, 8);
    bn_apply_lrelu<<<8388608 / 256, 256, 0, stream>>>(x2, mean, rstd, g2, b2, 255, 8);
    // 6. conv3: [128,256,16,16] -> [128,256,8,8]
    conv_ksplit<256, 16, 256, 4><<<BB * 256, 256, 0, stream>>>(x2, w3, x3);
    // 7. BN3 + lrelu
    bn_reduce<<<256, 256, 0, stream>>>(x3, mean, rstd, 256, 6);
    bn_apply_lrelu<<<2097152 / 256, 256, 0, stream>>>(x3, mean, rstd, g3, b3, 255, 6);
    // 8. conv4: [128,256,8,8] -> [128,512,4,4]
    conv_ksplit<256, 8, 512, 16><<<BB * 512, 256, 0, stream>>>(x3, w4, x4);
    // 9. BN4 + lrelu
    bn_reduce<<<512, 256, 0, stream>>>(x4, mean, rstd, 512, 4);
    bn_apply_lrelu<<<1048576 / 256, 256, 0, stream>>>(x4, mean, rstd, g4, b4, 511, 4);
    // 10. conv5 -> feat (directly into d_out rows, stride 1280)
    conv5_kernel<<<BB, 256, 0, stream>>>(x4, w5, out);
    // 11. Ms = feat @ T.reshape(1024,4096)   (A read from d_out, lda=1280)
    gemm_kernel<0, 0><<<dim3(128, 2), 256, 0, stream>>>(
        out, T, Ms, 128, 4096, 1024, 1280, 4096, 4096);
    // 12. minibatch discrimination -> out[:,1024:1280]
    mbd_kernel<<<BB, 256, 0, stream>>>(Ms, out);
}

// Round 2
// 687.607 us; speedup vs baseline: 19.5315x; 19.5315x over previous
//
#include <hip/hip_runtime.h>
#include <cstddef>

#define BB 128

typedef unsigned short u16;
typedef __attribute__((ext_vector_type(8))) short short8;
typedef __attribute__((ext_vector_type(4))) short short4v;
typedef __attribute__((ext_vector_type(4))) float f32x4;

constexpr int ilog2c(int v){ return v<=1 ? 0 : 1+ilog2c(v>>1); }

__device__ __forceinline__ u16 f2b(float f){
  union {float f; unsigned u;} x; x.f = f;
  unsigned u = x.u + 0x7fffu + ((x.u>>16)&1u);
  return (u16)(u>>16);
}
__device__ __forceinline__ float b2f(u16 h){
  union {unsigned u; float f;} x; x.u = ((unsigned)h)<<16;
  return x.f;
}

// ============ implicit-GEMM conv: 4x4 s2 p1, padded NHWC bf16 input ============
// y[p][oc] = sum_k A[p][k] * wtT[oc][k],  k = (kh*4+kw)*IC + ic
// STORE: 0 = bf16 [M][OC] plain; 1 = lrelu -> padded bf16 [(OH+2)^2][OC]; 2 = feat fp32 d_out permute
template<int IC, int OC, int OH, int STORE>
__global__ __launch_bounds__(256) void convmm(
    const u16* __restrict__ xp, const u16* __restrict__ wtT, void* __restrict__ yv)
{
  constexpr int OW = OH, S = OH*OW;
  constexpr int IHp = 2*OH+2, IWp = 2*OW+2;
  constexpr int KT = 16*IC;
  constexpr int LS = ilog2c(S), LOW = ilog2c(OW), L4 = ilog2c(4*IC);
  __shared__ u16 As[64*64];
  __shared__ u16 Bs[64*64];
  const int tid = threadIdx.x;
  const int n0 = blockIdx.x*64;
  const int m0 = blockIdx.y*64;
  const int wvid = tid>>6, l = tid&63;
  const int wm = wvid>>1, wn = wvid&1;

  // per-thread staging constants (pixel decomposition is k-independent)
  size_t abase[2]; int au[2];
  #pragma unroll
  for (int t=0;t<2;++t){
    int unit = tid + t*256;
    int r = unit>>3, us = unit&7;
    int u = us ^ (r&7);                 // pre-swizzled source unit
    int p = m0 + r;
    int b = p >> LS, s = p & (S-1);
    int oh = s >> LOW, ow = s & (OW-1);
    abase[t] = ((size_t)(b*IHp + 2*oh)*IWp + 2*ow)*IC;
    au[t] = u;
  }
  f32x4 acc[2][2] = {};

  for (int k0=0; k0<KT; k0+=64){
    #pragma unroll
    for (int t=0;t<2;++t){
      int unit = tid + t*256;
      int r = unit>>3, us = unit&7;
      int k = k0 + au[t]*8;
      int kh = k >> L4, koff = k & (4*IC-1);
      const u16* src = xp + abase[t] + (size_t)kh*IWp*IC + koff;
      *(float4*)(&As[r*64 + us*8]) = *(const float4*)src;
    }
    #pragma unroll
    for (int t=0;t<2;++t){
      int unit = tid + t*256;
      int r = unit>>3, us = unit&7;
      int u = us ^ (r&7);
      const u16* src = wtT + (size_t)(n0+r)*KT + k0 + u*8;
      *(float4*)(&Bs[r*64 + us*8]) = *(const float4*)src;
    }
    __syncthreads();
    #pragma unroll
    for (int kk=0;kk<2;++kk){
      short8 af[2], bfm[2];
      #pragma unroll
      for (int mi=0;mi<2;++mi){
        int row = wm*32 + mi*16 + (l&15);
        int u = (kk*4 + (l>>4)) ^ (row&7);
        af[mi] = *(const short8*)(&As[row*64 + u*8]);
      }
      #pragma unroll
      for (int ni=0;ni<2;++ni){
        int row = wn*32 + ni*16 + (l&15);
        int u = (kk*4 + (l>>4)) ^ (row&7);
        bfm[ni] = *(const short8*)(&Bs[row*64 + u*8]);
      }
      #pragma unroll
      for (int mi=0;mi<2;++mi)
        #pragma unroll
        for (int ni=0;ni<2;++ni)
          acc[mi][ni] = __builtin_amdgcn_mfma_f32_16x16x32_bf16(af[mi], bfm[ni], acc[mi][ni], 0,0,0);
    }
    __syncthreads();
  }
  #pragma unroll
  for (int mi=0;mi<2;++mi){
    #pragma unroll
    for (int ni=0;ni<2;++ni){
      #pragma unroll
      for (int r=0;r<4;++r){
        int row = m0 + wm*32 + mi*16 + (l>>4)*4 + r;
        int col = n0 + wn*32 + ni*16 + (l&15);
        float v = acc[mi][ni][r];
        if (STORE==0){
          ((u16*)yv)[(size_t)row*OC + col] = f2b(v);
        } else if (STORE==1){
          v = v>=0.f ? v : 0.2f*v;
          int b = row>>LS, s = row&(S-1);
          int oh = s>>LOW, ow = s&(OW-1);
          ((u16*)yv)[((size_t)(b*(OH+2) + oh+1)*(OW+2) + ow+1)*OC + col] = f2b(v);
        } else {
          int b = row>>2, s = row&3;
          ((float*)yv)[(size_t)b*1280 + col*4 + s] = v;
        }
      }
    }
  }
}

// ============ plain MFMA GEMM: C[m][n] = sum_k A[m][k]*B[n][k] ============
// B_FP32: B source is fp32 [N][K] (converted during staging), else bf16 [N][K]
// STORE: 0 = relu -> xp0 channel 3 (padded NHWC, IC=8); 1 = fp32 [m*4096+n]
template<int B_FP32, int STORE>
__global__ __launch_bounds__(256) void gemm_mm(
    const u16* __restrict__ A, const void* __restrict__ Bsrc, void* __restrict__ outv, int K)
{
  __shared__ u16 As[64*64];
  __shared__ u16 Bs[64*64];
  const int tid = threadIdx.x;
  const int n0 = blockIdx.x*64, m0 = blockIdx.y*64;
  const int wvid = tid>>6, l = tid&63;
  const int wm = wvid>>1, wn = wvid&1;
  f32x4 acc[2][2] = {};
  for (int k0=0;k0<K;k0+=64){
    #pragma unroll
    for (int t=0;t<2;++t){
      int unit = tid + t*256;
      int r = unit>>3, us = unit&7;
      int u = us ^ (r&7);
      *(float4*)(&As[r*64+us*8]) = *(const float4*)(A + (size_t)(m0+r)*K + k0 + u*8);
    }
    if (B_FP32){
      const float* Bf = (const float*)Bsrc;
      #pragma unroll
      for (int t=0;t<4;++t){
        int unit = tid + t*256;
        int r = unit>>4, u4 = unit&15;
        int u = u4>>1, half = u4&1;
        int us = u ^ (r&7);
        float4 v = *(const float4*)(Bf + (size_t)(n0+r)*K + k0 + u4*4);
        short4v o; o[0]=(short)f2b(v.x); o[1]=(short)f2b(v.y); o[2]=(short)f2b(v.z); o[3]=(short)f2b(v.w);
        *(short4v*)(&Bs[r*64 + us*8 + half*4]) = o;
      }
    } else {
      const u16* Bb = (const u16*)Bsrc;
      #pragma unroll
      for (int t=0;t<2;++t){
        int unit = tid + t*256;
        int r = unit>>3, us = unit&7;
        int u = us ^ (r&7);
        *(float4*)(&Bs[r*64+us*8]) = *(const float4*)(Bb + (size_t)(n0+r)*K + k0 + u*8);
      }
    }
    __syncthreads();
    #pragma unroll
    for (int kk=0;kk<2;++kk){
      short8 af[2], bfm[2];
      #pragma unroll
      for (int mi=0;mi<2;++mi){
        int row = wm*32 + mi*16 + (l&15);
        int u = (kk*4 + (l>>4)) ^ (row&7);
        af[mi] = *(const short8*)(&As[row*64 + u*8]);
      }
      #pragma unroll
      for (int ni=0;ni<2;++ni){
        int row = wn*32 + ni*16 + (l&15);
        int u = (kk*4 + (l>>4)) ^ (row&7);
        bfm[ni] = *(const short8*)(&Bs[row*64 + u*8]);
      }
      #pragma unroll
      for (int mi=0;mi<2;++mi)
        #pragma unroll
        for (int ni=0;ni<2;++ni)
          acc[mi][ni] = __builtin_amdgcn_mfma_f32_16x16x32_bf16(af[mi], bfm[ni], acc[mi][ni], 0,0,0);
    }
    __syncthreads();
  }
  #pragma unroll
  for (int mi=0;mi<2;++mi){
    #pragma unroll
    for (int ni=0;ni<2;++ni){
      #pragma unroll
      for (int r=0;r<4;++r){
        int row = m0 + wm*32 + mi*16 + (l>>4)*4 + r;
        int col = n0 + wn*32 + ni*16 + (l&15);
        float v = acc[mi][ni][r];
        if (STORE==0){
          v = fmaxf(v, 0.f);
          int h = col>>6, w = col&63;
          ((u16*)outv)[((size_t)(row*66 + h+1)*66 + w+1)*8 + 3] = f2b(v);
        } else {
          ((float*)outv)[(size_t)row*4096 + col] = v;
        }
      }
    }
  }
}

// ============ support kernels ============
__global__ __launch_bounds__(256) void wvb_convert(const float* __restrict__ in, u16* __restrict__ o){
  int i = blockIdx.x*256+threadIdx.x;
  o[i] = f2b(in[i]);
}

__global__ __launch_bounds__(256) void pack_x0(const float* __restrict__ img, u16* __restrict__ xp0){
  int idx = blockIdx.x*256+threadIdx.x;   // b*4096+s
  int b = idx>>12, s = idx&4095;
  int h = s>>6, w = s&63;
  u16* d = xp0 + ((size_t)(b*66 + h+1)*66 + w+1)*8;
  d[0] = f2b(img[(size_t)(b*3+0)*4096 + s]);
  d[1] = f2b(img[(size_t)(b*3+1)*4096 + s]);
  d[2] = f2b(img[(size_t)(b*3+2)*4096 + s]);
}

template<int IC, int ICP>
__global__ __launch_bounds__(256) void repack_w(const float* __restrict__ w, u16* __restrict__ wt){
  __shared__ float ls[IC*17];
  int oc = blockIdx.x;
  for (int i=threadIdx.x; i<IC*16; i+=256){
    int ic = i>>4, khkw = i&15;
    ls[ic*17+khkw] = w[(size_t)oc*IC*16 + i];
  }
  __syncthreads();
  constexpr int KT = 16*ICP;
  constexpr int LP = ilog2c(ICP);
  for (int k=threadIdx.x; k<KT; k+=256){
    int khkw = k >> LP, ic = k & (ICP-1);
    float v = (ic<IC) ? ls[ic*17+khkw] : 0.f;
    wt[(size_t)oc*KT + k] = f2b(v);
  }
}

__global__ __launch_bounds__(256) void transpose_T(const float* __restrict__ T, u16* __restrict__ Tt){
  __shared__ float tile[32][33];
  int kb = blockIdx.y*32, nb = blockIdx.x*32;
  int tx = threadIdx.x&31, ty = threadIdx.x>>5;  // ty 0..7
  #pragma unroll
  for (int i=0;i<32;i+=8)
    tile[ty+i][tx] = T[(size_t)(kb+ty+i)*4096 + nb+tx];
  __syncthreads();
  #pragma unroll
  for (int i=0;i<32;i+=8)
    Tt[(size_t)(nb+ty+i)*1024 + kb+tx] = f2b(tile[tx][ty+i]);
}

// deterministic two-stage BN stats: partials at stats[0..131072) sum, [131072..262144) sumsq
template<int C>
__global__ __launch_bounds__(C) void bn_stats(const u16* __restrict__ y, float* __restrict__ stats, int M){
  int c = threadIdx.x;
  float s=0.f, ss=0.f;
  for (int p=blockIdx.x; p<M; p+=256){
    float v = b2f(y[(size_t)p*C + c]);
    s += v; ss += v*v;
  }
  stats[blockIdx.x*512 + c] = s;
  stats[131072 + blockIdx.x*512 + c] = ss;
}

template<int C>
__global__ __launch_bounds__(C) void bn_finalize(float* __restrict__ stats, const float* __restrict__ g,
                                                 const float* __restrict__ be, float cnt){
  int c = threadIdx.x;
  float s=0.f, ss=0.f;
  for (int b=0;b<256;++b){ s += stats[b*512+c]; ss += stats[131072 + b*512+c]; }
  float m = s/cnt;
  float var = ss/cnt - m*m;
  float A = rsqrtf(var + 1e-5f)*g[c];
  stats[262144 + c] = A;
  stats[262144 + 512 + c] = be[c] - m*A;
}

template<int C, int OH>
__global__ __launch_bounds__(256) void bn_apply(const u16* __restrict__ y, const float* __restrict__ stats,
                                                u16* __restrict__ xp){
  constexpr int S = OH*OH, LS = ilog2c(S), LOW = ilog2c(OH);
  constexpr int CU = C/8, LCU = ilog2c(CU);
  int idx = blockIdx.x*256 + threadIdx.x;
  int p = idx >> LCU, cu = idx & (CU-1);
  short8 v8 = *(const short8*)(y + (size_t)p*C + cu*8);
  const float* Ap = stats + 262144;
  const float* Bp = stats + 262144 + 512;
  u16 o[8];
  #pragma unroll
  for (int j=0;j<8;++j){
    float v = b2f((u16)v8[j])*Ap[cu*8+j] + Bp[cu*8+j];
    o[j] = f2b(v>=0.f ? v : 0.2f*v);
  }
  int b = p>>LS, s = p&(S-1), oh = s>>LOW, ow = s&(OH-1);
  *(short8*)(xp + ((size_t)(b*(OH+2)+oh+1)*(OH+2)+ow+1)*C + cu*8) = *(short8*)o;
}

__global__ __launch_bounds__(256) void feat_convert(const float* __restrict__ out, u16* __restrict__ fb){
  int i = blockIdx.x*256+threadIdx.x;  // 131072
  fb[i] = f2b(out[(size_t)(i>>10)*1280 + (i&1023)]);
}

__global__ __launch_bounds__(256) void mbd_kernel(
    const float* __restrict__ Ms, float* __restrict__ out)
{
  const int i = blockIdx.x;
  const int o = threadIdx.x;
  float mi[16];
  #pragma unroll
  for (int u = 0; u < 4; ++u) {
    float4 v = *(const float4*)&Ms[(size_t)i * 4096 + o * 16 + u * 4];
    mi[u*4+0]=v.x; mi[u*4+1]=v.y; mi[u*4+2]=v.z; mi[u*4+3]=v.w;
  }
  float acc = 0.f;
  for (int j = 0; j < BB; ++j) {
    float d = 0.f;
    #pragma unroll
    for (int u = 0; u < 4; ++u) {
      float4 v = *(const float4*)&Ms[(size_t)j * 4096 + o * 16 + u * 4];
      d += fabsf(mi[u*4+0]-v.x) + fabsf(mi[u*4+1]-v.y) + fabsf(mi[u*4+2]-v.z) + fabsf(mi[u*4+3]-v.w);
    }
    acc += expf(-d);
  }
  out[(size_t)i * 1280 + 1024 + o] = acc;
}

__global__ void ws_too_small(float* out, int n){
  int idx = blockIdx.x*256+threadIdx.x;
  if (idx<n) out[idx] = -777.0f;
}

// ============ byte offsets (lifetime-packed) ============
// R0 [0, 37,879,808): xp1; after conv2 reused for y3/xp3/y4/xp4/Ms/featb/stats
// R1 [37,879,808, 59,113,472): xp2
// R2 [59,113,472, 75,890,688): y2
// R3 [75,890,688, 84,811,776): xp0
// R4 [84,811,776, 105,816,064): persistent weights
extern "C" void kernel_launch(void* const* d_in, const int* in_sizes, int n_in,
                              void* d_out, int out_size, void* d_ws, size_t ws_size,
                              hipStream_t stream)
{
  const float* image = (const float*)d_in[0];
  const float* wvec  = (const float*)d_in[1];
  const float* fc_w  = (const float*)d_in[2];
  const float* w1    = (const float*)d_in[3];
  const float* w2    = (const float*)d_in[4];
  const float* w3    = (const float*)d_in[5];
  const float* w4    = (const float*)d_in[6];
  const float* w5    = (const float*)d_in[7];
  const float* g2    = (const float*)d_in[8];
  const float* b2    = (const float*)d_in[9];
  const float* g3    = (const float*)d_in[10];
  const float* b3    = (const float*)d_in[11];
  const float* g4    = (const float*)d_in[12];
  const float* b4    = (const float*)d_in[13];
  const float* T     = (const float*)d_in[14];
  float* out = (float*)d_out;
  char* wsb = (char*)d_ws;

  const size_t NEED = 105816064ull;
  if (ws_size < NEED) {
    ws_too_small<<<(out_size + 255)/256, 256, 0, stream>>>(out, out_size);
    return;
  }

  u16* xp1   = (u16*)(wsb + 0);
  u16* y3    = (u16*)(wsb + 0);
  u16* xp3   = (u16*)(wsb + 4194304);
  u16* y4    = (u16*)(wsb + 10747904);
  u16* xp4   = (u16*)(wsb + 12845056);
  float* Ms  = (float*)(wsb + 17563648);
  u16* featb = (u16*)(wsb + 19660800);
  float* stats = (float*)(wsb + 19922944);     // 2,101,248 B
  u16* xp2   = (u16*)(wsb + 37879808);
  u16* y2    = (u16*)(wsb + 59113472);
  u16* xp0   = (u16*)(wsb + 75890688);
  u16* wt1T  = (u16*)(wsb + 84811776);         // 32,768
  u16* wt2T  = (u16*)(wsb + 84844544);         // 1,048,576
  u16* wt3T  = (u16*)(wsb + 85893120);         // 2,097,152
  u16* wt4T  = (u16*)(wsb + 87990272);         // 4,194,304
  u16* wt5T  = (u16*)(wsb + 92184576);         // 4,194,304
  u16* Tt    = (u16*)(wsb + 96378880);         // 8,388,608
  u16* wvb   = (u16*)(wsb + 104767488);        // 1,048,576 -> end 105,816,064

  // zero padded buffers (borders); interiors rewritten every call
  hipMemsetAsync(xp0, 0, 8921088, stream);
  hipMemsetAsync(xp1, 0, 37879808, stream);
  hipMemsetAsync(xp2, 0, 21233664, stream);

  // weight/input repacks
  wvb_convert<<<2048, 256, 0, stream>>>(wvec, wvb);
  repack_w<4,8><<<128, 256, 0, stream>>>(w1, wt1T);
  repack_w<128,128><<<256, 256, 0, stream>>>(w2, wt2T);
  repack_w<256,256><<<256, 256, 0, stream>>>(w3, wt3T);
  repack_w<256,256><<<512, 256, 0, stream>>>(w4, wt4T);
  repack_w<512,512><<<256, 256, 0, stream>>>(w5, wt5T);
  transpose_T<<<dim3(128,32), 256, 0, stream>>>(T, Tt);

  // FC -> xp0 channel 3 (relu), image -> xp0 channels 0..2
  gemm_mm<1,0><<<dim3(64,2), 256, 0, stream>>>(wvb, fc_w, xp0, 4096);
  pack_x0<<<2048, 256, 0, stream>>>(image, xp0);

  // conv1 + lrelu -> xp1 (padded bf16)
  convmm<8,128,32,1><<<dim3(2,2048), 256, 0, stream>>>(xp0, wt1T, xp1);
  // conv2 -> y2 (bf16)
  convmm<128,256,16,0><<<dim3(4,512), 256, 0, stream>>>(xp1, wt2T, y2);

  // xp1 region dead: zero xp3/xp4 borders now
  hipMemsetAsync(xp3, 0, 6553600, stream);
  hipMemsetAsync(xp4, 0, 4718592, stream);

  // BN2 + lrelu -> xp2
  bn_stats<256><<<256, 256, 0, stream>>>(y2, stats, 32768);
  bn_finalize<256><<<1, 256, 0, stream>>>(stats, g2, b2, 32768.f);
  bn_apply<256,16><<<4096, 256, 0, stream>>>(y2, stats, xp2);

  // conv3 -> y3; BN3 -> xp3
  convmm<256,256,8,0><<<dim3(4,128), 256, 0, stream>>>(xp2, wt3T, y3);
  bn_stats<256><<<256, 256, 0, stream>>>(y3, stats, 8192);
  bn_finalize<256><<<1, 256, 0, stream>>>(stats, g3, b3, 8192.f);
  bn_apply<256,8><<<1024, 256, 0, stream>>>(y3, stats, xp3);

  // conv4 -> y4; BN4 -> xp4
  convmm<256,512,4,0><<<dim3(8,32), 256, 0, stream>>>(xp3, wt4T, y4);
  bn_stats<512><<<256, 512, 0, stream>>>(y4, stats, 2048);
  bn_finalize<512><<<1, 512, 0, stream>>>(stats, g4, b4, 2048.f);
  bn_apply<512,4><<<512, 256, 0, stream>>>(y4, stats, xp4);

  // conv5 -> feat (fp32 into d_out, permuted)
  convmm<512,256,2,2><<<dim3(4,8), 256, 0, stream>>>(xp4, wt5T, out);

  // Ms = feat @ T  (bf16 MFMA), then mbd
  feat_convert<<<512, 256, 0, stream>>>(out, featb);
  gemm_mm<0,1><<<dim3(64,2), 256, 0, stream>>>(featb, Tt, Ms, 1024);
  mbd_kernel<<<128, 256, 0, stream>>>(Ms, out);
}

// Round 3
// 534.123 us; speedup vs baseline: 25.1441x; 1.2874x over previous
//
#include <hip/hip_runtime.h>
#include <cstddef>

#define BB 128

typedef unsigned short u16;
typedef __attribute__((ext_vector_type(8))) short short8;
typedef __attribute__((ext_vector_type(4))) short short4v;
typedef __attribute__((ext_vector_type(4))) float f32x4;

constexpr int ilog2c(int v){ return v<=1 ? 0 : 1+ilog2c(v>>1); }

__device__ __forceinline__ u16 f2b(float f){
  union {float f; unsigned u;} x; x.f = f;
  unsigned u = x.u + 0x7fffu + ((x.u>>16)&1u);
  return (u16)(u>>16);
}
__device__ __forceinline__ float b2f(u16 h){
  union {unsigned u; float f;} x; x.u = ((unsigned)h)<<16;
  return x.f;
}

// ============ implicit-GEMM conv: 4x4 s2 p1, padded NHWC bf16 input ============
// y[p][oc] = sum_k A[p][k] * wtT[oc][k],  k = (kh*4+kw)*IC + ic
// STORE: 0 = bf16 [M][OC]; 1 = lrelu -> padded bf16; 2 = feat fp32 d_out permute;
//        3 = fp32 partial [KSPLIT][M][OC] (blockIdx.z = split)
template<int IC, int OC, int OH, int STORE, int KSPLIT=1>
__global__ __launch_bounds__(256) void convmm(
    const u16* __restrict__ xp, const u16* __restrict__ wtT, void* __restrict__ yv)
{
  constexpr int OW = OH, S = OH*OW;
  constexpr int IHp = 2*OH+2, IWp = 2*OW+2;
  constexpr int KT = 16*IC;
  constexpr int KTS = KT / KSPLIT;
  constexpr int M = BB * S;
  constexpr int LS = ilog2c(S), LOW = ilog2c(OW), L4 = ilog2c(4*IC);
  __shared__ u16 As[64*64];
  __shared__ u16 Bs[64*64];
  const int tid = threadIdx.x;
  const int n0 = blockIdx.x*64;
  const int m0 = blockIdx.y*64;
  const int kbase = (KSPLIT>1) ? blockIdx.z*KTS : 0;
  const int wvid = tid>>6, l = tid&63;
  const int wm = wvid>>1, wn = wvid&1;

  size_t abase[2]; int au[2];
  #pragma unroll
  for (int t=0;t<2;++t){
    int unit = tid + t*256;
    int r = unit>>3, us = unit&7;
    int u = us ^ (r&7);
    int p = m0 + r;
    int b = p >> LS, s = p & (S-1);
    int oh = s >> LOW, ow = s & (OW-1);
    abase[t] = ((size_t)(b*IHp + 2*oh)*IWp + 2*ow)*IC;
    au[t] = u;
  }
  f32x4 acc[2][2] = {};

  for (int k0=kbase; k0<kbase+KTS; k0+=64){
    #pragma unroll
    for (int t=0;t<2;++t){
      int unit = tid + t*256;
      int r = unit>>3, us = unit&7;
      int k = k0 + au[t]*8;
      int kh = k >> L4, koff = k & (4*IC-1);
      const u16* src = xp + abase[t] + (size_t)kh*IWp*IC + koff;
      *(float4*)(&As[r*64 + us*8]) = *(const float4*)src;
    }
    #pragma unroll
    for (int t=0;t<2;++t){
      int unit = tid + t*256;
      int r = unit>>3, us = unit&7;
      int u = us ^ (r&7);
      const u16* src = wtT + (size_t)(n0+r)*KT + k0 + u*8;
      *(float4*)(&Bs[r*64 + us*8]) = *(const float4*)src;
    }
    __syncthreads();
    #pragma unroll
    for (int kk=0;kk<2;++kk){
      short8 af[2], bfm[2];
      #pragma unroll
      for (int mi=0;mi<2;++mi){
        int row = wm*32 + mi*16 + (l&15);
        int u = (kk*4 + (l>>4)) ^ (row&7);
        af[mi] = *(const short8*)(&As[row*64 + u*8]);
      }
      #pragma unroll
      for (int ni=0;ni<2;++ni){
        int row = wn*32 + ni*16 + (l&15);
        int u = (kk*4 + (l>>4)) ^ (row&7);
        bfm[ni] = *(const short8*)(&Bs[row*64 + u*8]);
      }
      #pragma unroll
      for (int mi=0;mi<2;++mi)
        #pragma unroll
        for (int ni=0;ni<2;++ni)
          acc[mi][ni] = __builtin_amdgcn_mfma_f32_16x16x32_bf16(af[mi], bfm[ni], acc[mi][ni], 0,0,0);
    }
    __syncthreads();
  }
  #pragma unroll
  for (int mi=0;mi<2;++mi){
    #pragma unroll
    for (int ni=0;ni<2;++ni){
      #pragma unroll
      for (int r=0;r<4;++r){
        int row = m0 + wm*32 + mi*16 + (l>>4)*4 + r;
        int col = n0 + wn*32 + ni*16 + (l&15);
        float v = acc[mi][ni][r];
        if (STORE==0){
          ((u16*)yv)[(size_t)row*OC + col] = f2b(v);
        } else if (STORE==1){
          v = v>=0.f ? v : 0.2f*v;
          int b = row>>LS, s = row&(S-1);
          int oh = s>>LOW, ow = s&(OW-1);
          ((u16*)yv)[((size_t)(b*(OH+2) + oh+1)*(OW+2) + ow+1)*OC + col] = f2b(v);
        } else if (STORE==2){
          int b = row>>2, s = row&3;
          ((float*)yv)[(size_t)b*1280 + col*4 + s] = v;
        } else {
          ((float*)yv)[((size_t)blockIdx.z*M + row)*OC + col] = v;
        }
      }
    }
  }
}

// ============ K-split GEMM, M=128 fixed, N=4096: part[ks][128][4096] ============
// C[m][n] = sum_k A[m][k]*B[n][k]; B_FP32: B is fp32 (converted in staging)
template<int B_FP32>
__global__ __launch_bounds__(256) void gemm128_split(
    const u16* __restrict__ A, const void* __restrict__ Bsrc,
    float* __restrict__ part, int K, int kchunk)
{
  __shared__ u16 As[128*64];
  __shared__ u16 Bs[64*64];
  const int tid = threadIdx.x;
  const int n0 = blockIdx.x*64;
  const int kbase = blockIdx.y*kchunk;
  const int wv = tid>>6, l = tid&63;
  f32x4 acc[2][4] = {};
  for (int k0=kbase; k0<kbase+kchunk; k0+=64){
    // A: 128 rows x 64 k
    #pragma unroll
    for (int t=0;t<4;++t){
      int unit = tid + t*256;
      int r = unit>>3, us = unit&7;
      int u = us ^ (r&7);
      *(float4*)(&As[r*64+us*8]) = *(const float4*)(A + (size_t)r*K + k0 + u*8);
    }
    if (B_FP32){
      const float* Bf = (const float*)Bsrc;
      #pragma unroll
      for (int t=0;t<4;++t){
        int unit = tid + t*256;
        int r = unit>>4, u4 = unit&15;
        int u = u4>>1, half = u4&1;
        int us = u ^ (r&7);
        float4 v = *(const float4*)(Bf + (size_t)(n0+r)*K + k0 + u4*4);
        short4v o; o[0]=(short)f2b(v.x); o[1]=(short)f2b(v.y); o[2]=(short)f2b(v.z); o[3]=(short)f2b(v.w);
        *(short4v*)(&Bs[r*64 + us*8 + half*4]) = o;
      }
    } else {
      const u16* Bb = (const u16*)Bsrc;
      #pragma unroll
      for (int t=0;t<2;++t){
        int unit = tid + t*256;
        int r = unit>>3, us = unit&7;
        int u = us ^ (r&7);
        *(float4*)(&Bs[r*64+us*8]) = *(const float4*)(Bb + (size_t)(n0+r)*K + k0 + u*8);
      }
    }
    __syncthreads();
    #pragma unroll
    for (int kk=0;kk<2;++kk){
      short8 af[2], bfm[4];
      #pragma unroll
      for (int mi=0;mi<2;++mi){
        int row = wv*32 + mi*16 + (l&15);
        int u = (kk*4 + (l>>4)) ^ (row&7);
        af[mi] = *(const short8*)(&As[row*64 + u*8]);
      }
      #pragma unroll
      for (int ni=0;ni<4;++ni){
        int row = ni*16 + (l&15);
        int u = (kk*4 + (l>>4)) ^ (row&7);
        bfm[ni] = *(const short8*)(&Bs[row*64 + u*8]);
      }
      #pragma unroll
      for (int mi=0;mi<2;++mi)
        #pragma unroll
        for (int ni=0;ni<4;++ni)
          acc[mi][ni] = __builtin_amdgcn_mfma_f32_16x16x32_bf16(af[mi], bfm[ni], acc[mi][ni], 0,0,0);
    }
    __syncthreads();
  }
  #pragma unroll
  for (int mi=0;mi<2;++mi){
    #pragma unroll
    for (int ni=0;ni<4;++ni){
      #pragma unroll
      for (int r=0;r<4;++r){
        int m = wv*32 + mi*16 + (l>>4)*4 + r;
        int n = n0 + ni*16 + (l&15);
        part[((size_t)blockIdx.y*128 + m)*4096 + n] = acc[mi][ni][r];
      }
    }
  }
}

// reduce NS partials of [128][4096]; STORE 0: relu -> xp0 ch3 ; 1: fp32 -> Ms
template<int NS, int STORE>
__global__ __launch_bounds__(256) void reduce_split(const float* __restrict__ part, void* __restrict__ outv)
{
  int idx = blockIdx.x*256 + threadIdx.x;
  float s = 0.f;
  #pragma unroll
  for (int i=0;i<NS;++i) s += part[(size_t)i*524288 + idx];
  if (STORE==0){
    float v = fmaxf(s, 0.f);
    int m = idx>>12, n = idx&4095;
    int h = n>>6, w2 = n&63;
    ((u16*)outv)[((size_t)(m*66 + h+1)*66 + w2+1)*8 + 3] = f2b(v);
  } else {
    ((float*)outv)[idx] = s;
  }
}

// reduce conv5 partials [8][512][256] -> d_out feat (permuted fp32) + featb (bf16 [128][1024])
__global__ __launch_bounds__(256) void conv5_reduce(const float* __restrict__ part,
                                                    float* __restrict__ out, u16* __restrict__ featb)
{
  int idx = blockIdx.x*256 + threadIdx.x;   // 131072
  float s = 0.f;
  #pragma unroll
  for (int i=0;i<8;++i) s += part[(size_t)i*131072 + idx];
  int row = idx>>8, col = idx&255;
  int b = row>>2, sp = row&3;
  out[(size_t)b*1280 + col*4 + sp] = s;
  featb[(size_t)b*1024 + col*4 + sp] = f2b(s);
}

// ============ support kernels ============
__global__ __launch_bounds__(256) void wvb_convert(const float* __restrict__ in, u16* __restrict__ o){
  int i = blockIdx.x*256+threadIdx.x;
  o[i] = f2b(in[i]);
}

__global__ __launch_bounds__(256) void pack_x0(const float* __restrict__ img, u16* __restrict__ xp0){
  int idx = blockIdx.x*256+threadIdx.x;   // b*4096+s
  int b = idx>>12, s = idx&4095;
  int h = s>>6, w = s&63;
  u16* d = xp0 + ((size_t)(b*66 + h+1)*66 + w+1)*8;
  d[0] = f2b(img[(size_t)(b*3+0)*4096 + s]);
  d[1] = f2b(img[(size_t)(b*3+1)*4096 + s]);
  d[2] = f2b(img[(size_t)(b*3+2)*4096 + s]);
}

template<int IC, int ICP>
__global__ __launch_bounds__(256) void repack_w(const float* __restrict__ w, u16* __restrict__ wt){
  __shared__ float ls[IC*17];
  int oc = blockIdx.x;
  for (int i=threadIdx.x; i<IC*16; i+=256){
    int ic = i>>4, khkw = i&15;
    ls[ic*17+khkw] = w[(size_t)oc*IC*16 + i];
  }
  __syncthreads();
  constexpr int KT = 16*ICP;
  constexpr int LP = ilog2c(ICP);
  for (int k=threadIdx.x; k<KT; k+=256){
    int khkw = k >> LP, ic = k & (ICP-1);
    float v = (ic<IC) ? ls[ic*17+khkw] : 0.f;
    wt[(size_t)oc*KT + k] = f2b(v);
  }
}

__global__ __launch_bounds__(256) void transpose_T(const float* __restrict__ T, u16* __restrict__ Tt){
  __shared__ float tile[32][33];
  int kb = blockIdx.y*32, nb = blockIdx.x*32;
  int tx = threadIdx.x&31, ty = threadIdx.x>>5;
  #pragma unroll
  for (int i=0;i<32;i+=8)
    tile[ty+i][tx] = T[(size_t)(kb+ty+i)*4096 + nb+tx];
  __syncthreads();
  #pragma unroll
  for (int i=0;i<32;i+=8)
    Tt[(size_t)(nb+ty+i)*1024 + kb+tx] = f2b(tile[tx][ty+i]);
}

// deterministic two-stage BN stats
template<int C>
__global__ __launch_bounds__(C) void bn_stats(const u16* __restrict__ y, float* __restrict__ stats, int M){
  int c = threadIdx.x;
  float s=0.f, ss=0.f;
  for (int p=blockIdx.x; p<M; p+=256){
    float v = b2f(y[(size_t)p*C + c]);
    s += v; ss += v*v;
  }
  stats[blockIdx.x*512 + c] = s;
  stats[131072 + blockIdx.x*512 + c] = ss;
}

template<int C>
__global__ __launch_bounds__(C) void bn_finalize(float* __restrict__ stats, const float* __restrict__ g,
                                                 const float* __restrict__ be, float cnt){
  int c = threadIdx.x;
  float s=0.f, ss=0.f;
  for (int b=0;b<256;++b){ s += stats[b*512+c]; ss += stats[131072 + b*512+c]; }
  float m = s/cnt;
  float var = ss/cnt - m*m;
  float A = rsqrtf(var + 1e-5f)*g[c];
  stats[262144 + c] = A;
  stats[262144 + 512 + c] = be[c] - m*A;
}

template<int C, int OH>
__global__ __launch_bounds__(256) void bn_apply(const u16* __restrict__ y, const float* __restrict__ stats,
                                                u16* __restrict__ xp){
  constexpr int S = OH*OH, LS = ilog2c(S), LOW = ilog2c(OH);
  constexpr int CU = C/8, LCU = ilog2c(CU);
  int idx = blockIdx.x*256 + threadIdx.x;
  int p = idx >> LCU, cu = idx & (CU-1);
  short8 v8 = *(const short8*)(y + (size_t)p*C + cu*8);
  const float* Ap = stats + 262144;
  const float* Bp = stats + 262144 + 512;
  u16 o[8];
  #pragma unroll
  for (int j=0;j<8;++j){
    float v = b2f((u16)v8[j])*Ap[cu*8+j] + Bp[cu*8+j];
    o[j] = f2b(v>=0.f ? v : 0.2f*v);
  }
  int b = p>>LS, s = p&(S-1), oh = s>>LOW, ow = s&(OH-1);
  *(short8*)(xp + ((size_t)(b*(OH+2)+oh+1)*(OH+2)+ow+1)*C + cu*8) = *(short8*)o;
}

__global__ __launch_bounds__(256) void mbd_kernel(
    const float* __restrict__ Ms, float* __restrict__ out)
{
  const int i = blockIdx.x;
  const int o = threadIdx.x;
  float mi[16];
  #pragma unroll
  for (int u = 0; u < 4; ++u) {
    float4 v = *(const float4*)&Ms[(size_t)i * 4096 + o * 16 + u * 4];
    mi[u*4+0]=v.x; mi[u*4+1]=v.y; mi[u*4+2]=v.z; mi[u*4+3]=v.w;
  }
  float acc = 0.f;
  for (int j = 0; j < BB; ++j) {
    float d = 0.f;
    #pragma unroll
    for (int u = 0; u < 4; ++u) {
      float4 v = *(const float4*)&Ms[(size_t)j * 4096 + o * 16 + u * 4];
      d += fabsf(mi[u*4+0]-v.x) + fabsf(mi[u*4+1]-v.y) + fabsf(mi[u*4+2]-v.z) + fabsf(mi[u*4+3]-v.w);
    }
    acc += expf(-d);
  }
  out[(size_t)i * 1280 + 1024 + o] = acc;
}

__global__ void ws_too_small(float* out, int n){
  int idx = blockIdx.x*256+threadIdx.x;
  if (idx<n) out[idx] = -777.0f;
}

// ============ byte offsets (lifetime-packed) ============
extern "C" void kernel_launch(void* const* d_in, const int* in_sizes, int n_in,
                              void* d_out, int out_size, void* d_ws, size_t ws_size,
                              hipStream_t stream)
{
  const float* image = (const float*)d_in[0];
  const float* wvec  = (const float*)d_in[1];
  const float* fc_w  = (const float*)d_in[2];
  const float* w1    = (const float*)d_in[3];
  const float* w2    = (const float*)d_in[4];
  const float* w3    = (const float*)d_in[5];
  const float* w4    = (const float*)d_in[6];
  const float* w5    = (const float*)d_in[7];
  const float* g2    = (const float*)d_in[8];
  const float* b2    = (const float*)d_in[9];
  const float* g3    = (const float*)d_in[10];
  const float* b3    = (const float*)d_in[11];
  const float* g4    = (const float*)d_in[12];
  const float* b4    = (const float*)d_in[13];
  const float* T     = (const float*)d_in[14];
  float* out = (float*)d_out;
  char* wsb = (char*)d_ws;

  const size_t NEED = 105816064ull;
  if (ws_size < NEED) {
    ws_too_small<<<(out_size + 255)/256, 256, 0, stream>>>(out, out_size);
    return;
  }

  u16* xp1   = (u16*)(wsb + 0);
  u16* y3    = (u16*)(wsb + 0);
  u16* xp3   = (u16*)(wsb + 4194304);
  u16* y4    = (u16*)(wsb + 10747904);
  u16* xp4   = (u16*)(wsb + 12845056);
  float* Ms  = (float*)(wsb + 17563648);
  u16* featb = (u16*)(wsb + 19660800);
  float* stats = (float*)(wsb + 19922944);
  u16* xp2   = (u16*)(wsb + 37879808);
  float* c5part = (float*)(wsb + 37879808);    // reuses xp2 region after conv3
  u16* y2    = (u16*)(wsb + 59113472);
  float* gpart  = (float*)(wsb + 59113472);    // reuses y2 region (16,777,216 B exactly)
  u16* xp0   = (u16*)(wsb + 75890688);
  u16* wt1T  = (u16*)(wsb + 84811776);
  u16* wt2T  = (u16*)(wsb + 84844544);
  u16* wt3T  = (u16*)(wsb + 85893120);
  u16* wt4T  = (u16*)(wsb + 87990272);
  u16* wt5T  = (u16*)(wsb + 92184576);
  u16* Tt    = (u16*)(wsb + 96378880);
  u16* wvb   = (u16*)(wsb + 104767488);

  // zero padded buffers (borders)
  hipMemsetAsync(xp0, 0, 8921088, stream);
  hipMemsetAsync(xp1, 0, 37879808, stream);
  hipMemsetAsync(xp2, 0, 21233664, stream);

  // repacks
  wvb_convert<<<2048, 256, 0, stream>>>(wvec, wvb);
  repack_w<4,8><<<128, 256, 0, stream>>>(w1, wt1T);
  repack_w<128,128><<<256, 256, 0, stream>>>(w2, wt2T);
  repack_w<256,256><<<256, 256, 0, stream>>>(w3, wt3T);
  repack_w<256,256><<<512, 256, 0, stream>>>(w4, wt4T);
  repack_w<512,512><<<256, 256, 0, stream>>>(w5, wt5T);
  transpose_T<<<dim3(128,32), 256, 0, stream>>>(T, Tt);

  // FC (K-split 8 x 512) -> partials in y2 region -> relu-reduce into xp0 ch3
  gemm128_split<1><<<dim3(64,8), 256, 0, stream>>>(wvb, fc_w, gpart, 4096, 512);
  reduce_split<8,0><<<2048, 256, 0, stream>>>(gpart, xp0);
  pack_x0<<<2048, 256, 0, stream>>>(image, xp0);

  // conv1 + lrelu -> xp1
  convmm<8,128,32,1><<<dim3(2,2048), 256, 0, stream>>>(xp0, wt1T, xp1);
  // conv2 -> y2 (overwrites FC partials, now dead)
  convmm<128,256,16,0><<<dim3(4,512), 256, 0, stream>>>(xp1, wt2T, y2);

  // xp1 region dead: zero xp3/xp4 borders
  hipMemsetAsync(xp3, 0, 6553600, stream);
  hipMemsetAsync(xp4, 0, 4718592, stream);

  // BN2 + lrelu -> xp2
  bn_stats<256><<<256, 256, 0, stream>>>(y2, stats, 32768);
  bn_finalize<256><<<1, 256, 0, stream>>>(stats, g2, b2, 32768.f);
  bn_apply<256,16><<<4096, 256, 0, stream>>>(y2, stats, xp2);

  // conv3 -> y3; BN3 -> xp3
  convmm<256,256,8,0><<<dim3(4,128), 256, 0, stream>>>(xp2, wt3T, y3);
  bn_stats<256><<<256, 256, 0, stream>>>(y3, stats, 8192);
  bn_finalize<256><<<1, 256, 0, stream>>>(stats, g3, b3, 8192.f);
  bn_apply<256,8><<<1024, 256, 0, stream>>>(y3, stats, xp3);

  // conv4 -> y4; BN4 -> xp4
  convmm<256,512,4,0><<<dim3(8,32), 256, 0, stream>>>(xp3, wt4T, y4);
  bn_stats<512><<<256, 512, 0, stream>>>(y4, stats, 2048);
  bn_finalize<512><<<1, 512, 0, stream>>>(stats, g4, b4, 2048.f);
  bn_apply<512,4><<<512, 256, 0, stream>>>(y4, stats, xp4);

  // conv5 (K-split 8) -> partials in xp2 region (dead after conv3) -> out feat + featb
  convmm<512,256,2,3,8><<<dim3(4,8,8), 256, 0, stream>>>(xp4, wt5T, c5part);
  conv5_reduce<<<512, 256, 0, stream>>>(c5part, out, featb);

  // Ms = feat @ T (K-split 8 x 128) -> partials in y2 region (dead) -> Ms fp32
  gemm128_split<0><<<dim3(64,8), 256, 0, stream>>>(featb, Tt, gpart, 1024, 128);
  reduce_split<8,1><<<2048, 256, 0, stream>>>(gpart, Ms);
  mbd_kernel<<<128, 256, 0, stream>>>(Ms, out);
}

// Round 4
// 356.647 us; speedup vs baseline: 37.6563x; 1.4976x over previous
//
#include <hip/hip_runtime.h>
#include <cstddef>

#define BB 128

typedef unsigned short u16;
typedef __attribute__((ext_vector_type(8))) short short8;
typedef __attribute__((ext_vector_type(4))) short short4v;
typedef __attribute__((ext_vector_type(4))) float f32x4;

constexpr int ilog2c(int v){ return v<=1 ? 0 : 1+ilog2c(v>>1); }

__device__ __forceinline__ u16 f2b(float f){
  union {float f; unsigned u;} x; x.f = f;
  unsigned u = x.u + 0x7fffu + ((x.u>>16)&1u);
  return (u16)(u>>16);
}
__device__ __forceinline__ float b2f(u16 h){
  union {unsigned u; float f;} x; x.u = ((unsigned)h)<<16;
  return x.f;
}

#define GLOAD_LDS16(gsrc, ldsdst) \
  __builtin_amdgcn_global_load_lds((const __attribute__((address_space(1))) void*)(gsrc), \
      (__attribute__((address_space(3))) void*)(ldsdst), 16, 0, 0)

// ============ implicit-GEMM conv v2: 128x128 tile, global_load_lds staging ============
// y[p][oc] = sum_k A[p][k] * wtT[oc][k],  k = (kh*4+kw)*IC + ic
// STORE: 0 = bf16 [M][OC]; 1 = lrelu -> padded bf16; 3 = fp32 partial [KSPLIT][M][OC]
template<int IC, int OC, int OH, int STORE, int KSPLIT=1>
__global__ __launch_bounds__(256) void convmm2(
    const u16* __restrict__ xp, const u16* __restrict__ wtT, void* __restrict__ yv)
{
  constexpr int OW = OH, S = OH*OW;
  constexpr int IHp = 2*OH+2, IWp = 2*OW+2;
  constexpr int KT = 16*IC;
  constexpr int KTS = KT / KSPLIT;
  constexpr int M = BB * S;
  constexpr int LS = ilog2c(S), LOW = ilog2c(OW), L4 = ilog2c(4*IC);
  __shared__ u16 As[128*64];
  __shared__ u16 Bs[128*64];
  const int tid = threadIdx.x;
  const int n0 = blockIdx.x*128;
  const int m0 = blockIdx.y*128;
  const int kbase = (KSPLIT>1) ? blockIdx.z*KTS : 0;
  const int wave = tid>>6, l = tid&63;
  const int wm = wave>>1, wn = wave&1;

  // per-thread A staging constants: unit = tid + t*256 -> (row r, slot us)
  size_t abase[4]; int au[4];
  #pragma unroll
  for (int t=0;t<4;++t){
    int unit = tid + t*256;
    int r = unit>>3, us = unit&7;
    au[t] = us ^ (r&7);                 // pre-swizzled source k-chunk
    int p = m0 + r;
    int b = p >> LS, s = p & (S-1);
    int oh = s >> LOW, ow = s & (OW-1);
    abase[t] = ((size_t)(b*IHp + 2*oh)*IWp + 2*ow)*IC;
  }
  // B staging constants
  const u16* bsrc[4];
  #pragma unroll
  for (int t=0;t<4;++t){
    int unit = tid + t*256;
    int r = unit>>3, us = unit&7;
    int u = us ^ (r&7);
    bsrc[t] = wtT + (size_t)(n0+r)*KT + u*8;
  }

  f32x4 acc[4][4] = {};

  for (int k0=kbase; k0<kbase+KTS; k0+=64){
    #pragma unroll
    for (int t=0;t<4;++t){
      int k = k0 + au[t]*8;
      int kh = k >> L4, koff = k & (4*IC-1);
      const u16* src = xp + abase[t] + (size_t)kh*IWp*IC + koff;
      GLOAD_LDS16(src, &As[(size_t)(t*256 + wave*64)*8]);
    }
    #pragma unroll
    for (int t=0;t<4;++t){
      GLOAD_LDS16(bsrc[t] + k0, &Bs[(size_t)(t*256 + wave*64)*8]);
    }
    __syncthreads();
    #pragma unroll
    for (int kk=0;kk<2;++kk){
      short8 af[4], bfm[4];
      #pragma unroll
      for (int mi=0;mi<4;++mi){
        int row = wm*64 + mi*16 + (l&15);
        int u = (kk*4 + (l>>4)) ^ (row&7);
        af[mi] = *(const short8*)(&As[row*64 + u*8]);
      }
      #pragma unroll
      for (int ni=0;ni<4;++ni){
        int row = wn*64 + ni*16 + (l&15);
        int u = (kk*4 + (l>>4)) ^ (row&7);
        bfm[ni] = *(const short8*)(&Bs[row*64 + u*8]);
      }
      #pragma unroll
      for (int mi=0;mi<4;++mi)
        #pragma unroll
        for (int ni=0;ni<4;++ni)
          acc[mi][ni] = __builtin_amdgcn_mfma_f32_16x16x32_bf16(af[mi], bfm[ni], acc[mi][ni], 0,0,0);
    }
    __syncthreads();
  }
  #pragma unroll
  for (int mi=0;mi<4;++mi){
    #pragma unroll
    for (int ni=0;ni<4;++ni){
      #pragma unroll
      for (int r=0;r<4;++r){
        int row = m0 + wm*64 + mi*16 + (l>>4)*4 + r;
        int col = n0 + wn*64 + ni*16 + (l&15);
        float v = acc[mi][ni][r];
        if (STORE==0){
          ((u16*)yv)[(size_t)row*OC + col] = f2b(v);
        } else if (STORE==1){
          v = v>=0.f ? v : 0.2f*v;
          int b = row>>LS, s = row&(S-1);
          int oh = s>>LOW, ow = s&(OW-1);
          ((u16*)yv)[((size_t)(b*(OH+2) + oh+1)*(OW+2) + ow+1)*OC + col] = f2b(v);
        } else {
          ((float*)yv)[((size_t)blockIdx.z*M + row)*OC + col] = v;
        }
      }
    }
  }
}

// ============ implicit-GEMM conv (64x64 tile) — kept for conv5 K-split ============
template<int IC, int OC, int OH, int STORE, int KSPLIT=1>
__global__ __launch_bounds__(256) void convmm(
    const u16* __restrict__ xp, const u16* __restrict__ wtT, void* __restrict__ yv)
{
  constexpr int OW = OH, S = OH*OW;
  constexpr int IHp = 2*OH+2, IWp = 2*OW+2;
  constexpr int KT = 16*IC;
  constexpr int KTS = KT / KSPLIT;
  constexpr int M = BB * S;
  constexpr int LS = ilog2c(S), LOW = ilog2c(OW), L4 = ilog2c(4*IC);
  __shared__ u16 As[64*64];
  __shared__ u16 Bs[64*64];
  const int tid = threadIdx.x;
  const int n0 = blockIdx.x*64;
  const int m0 = blockIdx.y*64;
  const int kbase = (KSPLIT>1) ? blockIdx.z*KTS : 0;
  const int wvid = tid>>6, l = tid&63;
  const int wm = wvid>>1, wn = wvid&1;

  size_t abase[2]; int au[2];
  #pragma unroll
  for (int t=0;t<2;++t){
    int unit = tid + t*256;
    int r = unit>>3, us = unit&7;
    int u = us ^ (r&7);
    int p = m0 + r;
    int b = p >> LS, s = p & (S-1);
    int oh = s >> LOW, ow = s & (OW-1);
    abase[t] = ((size_t)(b*IHp + 2*oh)*IWp + 2*ow)*IC;
    au[t] = u;
  }
  f32x4 acc[2][2] = {};

  for (int k0=kbase; k0<kbase+KTS; k0+=64){
    #pragma unroll
    for (int t=0;t<2;++t){
      int unit = tid + t*256;
      int r = unit>>3, us = unit&7;
      int k = k0 + au[t]*8;
      int kh = k >> L4, koff = k & (4*IC-1);
      const u16* src = xp + abase[t] + (size_t)kh*IWp*IC + koff;
      *(float4*)(&As[r*64 + us*8]) = *(const float4*)src;
    }
    #pragma unroll
    for (int t=0;t<2;++t){
      int unit = tid + t*256;
      int r = unit>>3, us = unit&7;
      int u = us ^ (r&7);
      const u16* src = wtT + (size_t)(n0+r)*KT + k0 + u*8;
      *(float4*)(&Bs[r*64 + us*8]) = *(const float4*)src;
    }
    __syncthreads();
    #pragma unroll
    for (int kk=0;kk<2;++kk){
      short8 af[2], bfm[2];
      #pragma unroll
      for (int mi=0;mi<2;++mi){
        int row = wm*32 + mi*16 + (l&15);
        int u = (kk*4 + (l>>4)) ^ (row&7);
        af[mi] = *(const short8*)(&As[row*64 + u*8]);
      }
      #pragma unroll
      for (int ni=0;ni<2;++ni){
        int row = wn*32 + ni*16 + (l&15);
        int u = (kk*4 + (l>>4)) ^ (row&7);
        bfm[ni] = *(const short8*)(&Bs[row*64 + u*8]);
      }
      #pragma unroll
      for (int mi=0;mi<2;++mi)
        #pragma unroll
        for (int ni=0;ni<2;++ni)
          acc[mi][ni] = __builtin_amdgcn_mfma_f32_16x16x32_bf16(af[mi], bfm[ni], acc[mi][ni], 0,0,0);
    }
    __syncthreads();
  }
  #pragma unroll
  for (int mi=0;mi<2;++mi){
    #pragma unroll
    for (int ni=0;ni<2;++ni){
      #pragma unroll
      for (int r=0;r<4;++r){
        int row = m0 + wm*32 + mi*16 + (l>>4)*4 + r;
        int col = n0 + wn*32 + ni*16 + (l&15);
        float v = acc[mi][ni][r];
        if (STORE==0){
          ((u16*)yv)[(size_t)row*OC + col] = f2b(v);
        } else if (STORE==1){
          v = v>=0.f ? v : 0.2f*v;
          int b = row>>LS, s = row&(S-1);
          int oh = s>>LOW, ow = s&(OW-1);
          ((u16*)yv)[((size_t)(b*(OH+2) + oh+1)*(OW+2) + ow+1)*OC + col] = f2b(v);
        } else if (STORE==2){
          int b = row>>2, s = row&3;
          ((float*)yv)[(size_t)b*1280 + col*4 + s] = v;
        } else {
          ((float*)yv)[((size_t)blockIdx.z*M + row)*OC + col] = v;
        }
      }
    }
  }
}

// ============ K-split GEMM, M=128 fixed, N=4096 ============
template<int B_FP32>
__global__ __launch_bounds__(256) void gemm128_split(
    const u16* __restrict__ A, const void* __restrict__ Bsrc,
    float* __restrict__ part, int K, int kchunk)
{
  __shared__ u16 As[128*64];
  __shared__ u16 Bs[64*64];
  const int tid = threadIdx.x;
  const int n0 = blockIdx.x*64;
  const int kbase = blockIdx.y*kchunk;
  const int wv = tid>>6, l = tid&63;
  f32x4 acc[2][4] = {};
  for (int k0=kbase; k0<kbase+kchunk; k0+=64){
    #pragma unroll
    for (int t=0;t<4;++t){
      int unit = tid + t*256;
      int r = unit>>3, us = unit&7;
      int u = us ^ (r&7);
      *(float4*)(&As[r*64+us*8]) = *(const float4*)(A + (size_t)r*K + k0 + u*8);
    }
    if (B_FP32){
      const float* Bf = (const float*)Bsrc;
      #pragma unroll
      for (int t=0;t<4;++t){
        int unit = tid + t*256;
        int r = unit>>4, u4 = unit&15;
        int u = u4>>1, half = u4&1;
        int us = u ^ (r&7);
        float4 v = *(const float4*)(Bf + (size_t)(n0+r)*K + k0 + u4*4);
        short4v o; o[0]=(short)f2b(v.x); o[1]=(short)f2b(v.y); o[2]=(short)f2b(v.z); o[3]=(short)f2b(v.w);
        *(short4v*)(&Bs[r*64 + us*8 + half*4]) = o;
      }
    } else {
      const u16* Bb = (const u16*)Bsrc;
      #pragma unroll
      for (int t=0;t<2;++t){
        int unit = tid + t*256;
        int r = unit>>3, us = unit&7;
        int u = us ^ (r&7);
        *(float4*)(&Bs[r*64+us*8]) = *(const float4*)(Bb + (size_t)(n0+r)*K + k0 + u*8);
      }
    }
    __syncthreads();
    #pragma unroll
    for (int kk=0;kk<2;++kk){
      short8 af[2], bfm[4];
      #pragma unroll
      for (int mi=0;mi<2;++mi){
        int row = wv*32 + mi*16 + (l&15);
        int u = (kk*4 + (l>>4)) ^ (row&7);
        af[mi] = *(const short8*)(&As[row*64 + u*8]);
      }
      #pragma unroll
      for (int ni=0;ni<4;++ni){
        int row = ni*16 + (l&15);
        int u = (kk*4 + (l>>4)) ^ (row&7);
        bfm[ni] = *(const short8*)(&Bs[row*64 + u*8]);
      }
      #pragma unroll
      for (int mi=0;mi<2;++mi)
        #pragma unroll
        for (int ni=0;ni<4;++ni)
          acc[mi][ni] = __builtin_amdgcn_mfma_f32_16x16x32_bf16(af[mi], bfm[ni], acc[mi][ni], 0,0,0);
    }
    __syncthreads();
  }
  #pragma unroll
  for (int mi=0;mi<2;++mi){
    #pragma unroll
    for (int ni=0;ni<4;++ni){
      #pragma unroll
      for (int r=0;r<4;++r){
        int m = wv*32 + mi*16 + (l>>4)*4 + r;
        int n = n0 + ni*16 + (l&15);
        part[((size_t)blockIdx.y*128 + m)*4096 + n] = acc[mi][ni][r];
      }
    }
  }
}

// reduce NS partials of [128][4096]; STORE 0: relu -> xp0 ch3 ; 1: fp32 -> Ms
template<int NS, int STORE>
__global__ __launch_bounds__(256) void reduce_split(const float* __restrict__ part, void* __restrict__ outv)
{
  int idx = blockIdx.x*256 + threadIdx.x;
  float s = 0.f;
  #pragma unroll
  for (int i=0;i<NS;++i) s += part[(size_t)i*524288 + idx];
  if (STORE==0){
    float v = fmaxf(s, 0.f);
    int m = idx>>12, n = idx&4095;
    int h = n>>6, w2 = n&63;
    ((u16*)outv)[((size_t)(m*66 + h+1)*66 + w2+1)*8 + 3] = f2b(v);
  } else {
    ((float*)outv)[idx] = s;
  }
}

// reduce NS fp32 partials (vectorized x4) -> bf16
template<int NS>
__global__ __launch_bounds__(256) void reduce_part(const float* __restrict__ part,
                                                   u16* __restrict__ out, int total4)
{
  int idx = blockIdx.x*256 + threadIdx.x;   // over total/4
  float4 s = {0.f,0.f,0.f,0.f};
  #pragma unroll
  for (int i=0;i<NS;++i){
    float4 v = *(const float4*)(part + ((size_t)i*total4 + idx)*4);
    s.x+=v.x; s.y+=v.y; s.z+=v.z; s.w+=v.w;
  }
  short4v o; o[0]=(short)f2b(s.x); o[1]=(short)f2b(s.y); o[2]=(short)f2b(s.z); o[3]=(short)f2b(s.w);
  *(short4v*)(out + (size_t)idx*4) = o;
}

// reduce conv5 partials [8][512][256] -> d_out feat (permuted fp32) + featb (bf16 [128][1024])
__global__ __launch_bounds__(256) void conv5_reduce(const float* __restrict__ part,
                                                    float* __restrict__ out, u16* __restrict__ featb)
{
  int idx = blockIdx.x*256 + threadIdx.x;   // 131072
  float s = 0.f;
  #pragma unroll
  for (int i=0;i<8;++i) s += part[(size_t)i*131072 + idx];
  int row = idx>>8, col = idx&255;
  int b = row>>2, sp = row&3;
  out[(size_t)b*1280 + col*4 + sp] = s;
  featb[(size_t)b*1024 + col*4 + sp] = f2b(s);
}

// ============ support kernels ============
__global__ __launch_bounds__(256) void wvb_convert(const float* __restrict__ in, u16* __restrict__ o){
  int i = blockIdx.x*256+threadIdx.x;
  o[i] = f2b(in[i]);
}

__global__ __launch_bounds__(256) void pack_x0(const float* __restrict__ img, u16* __restrict__ xp0){
  int idx = blockIdx.x*256+threadIdx.x;   // b*4096+s
  int b = idx>>12, s = idx&4095;
  int h = s>>6, w = s&63;
  u16* d = xp0 + ((size_t)(b*66 + h+1)*66 + w+1)*8;
  d[0] = f2b(img[(size_t)(b*3+0)*4096 + s]);
  d[1] = f2b(img[(size_t)(b*3+1)*4096 + s]);
  d[2] = f2b(img[(size_t)(b*3+2)*4096 + s]);
}

template<int IC, int ICP>
__global__ __launch_bounds__(256) void repack_w(const float* __restrict__ w, u16* __restrict__ wt){
  __shared__ float ls[IC*17];
  int oc = blockIdx.x;
  for (int i=threadIdx.x; i<IC*16; i+=256){
    int ic = i>>4, khkw = i&15;
    ls[ic*17+khkw] = w[(size_t)oc*IC*16 + i];
  }
  __syncthreads();
  constexpr int KT = 16*ICP;
  constexpr int LP = ilog2c(ICP);
  for (int k=threadIdx.x; k<KT; k+=256){
    int khkw = k >> LP, ic = k & (ICP-1);
    float v = (ic<IC) ? ls[ic*17+khkw] : 0.f;
    wt[(size_t)oc*KT + k] = f2b(v);
  }
}

__global__ __launch_bounds__(256) void transpose_T(const float* __restrict__ T, u16* __restrict__ Tt){
  __shared__ float tile[32][33];
  int kb = blockIdx.y*32, nb = blockIdx.x*32;
  int tx = threadIdx.x&31, ty = threadIdx.x>>5;
  #pragma unroll
  for (int i=0;i<32;i+=8)
    tile[ty+i][tx] = T[(size_t)(kb+ty+i)*4096 + nb+tx];
  __syncthreads();
  #pragma unroll
  for (int i=0;i<32;i+=8)
    Tt[(size_t)(nb+ty+i)*1024 + kb+tx] = f2b(tile[tx][ty+i]);
}

// deterministic two-stage BN stats, coalesced short8 loads
template<int C>
__global__ __launch_bounds__(256) void bn_stats2(const u16* __restrict__ y, float* __restrict__ stats, int Mblk){
  constexpr int CU = C/8, NR = 256/CU, LCU = ilog2c(CU);
  __shared__ float red[NR*C];
  const int cu = threadIdx.x & (CU-1);
  const int rg = threadIdx.x >> LCU;
  const int base = blockIdx.x*Mblk;
  float s[8] = {}, ss[8] = {};
  for (int p = base+rg; p < base+Mblk; p += NR){
    short8 v = *(const short8*)(y + (size_t)p*C + cu*8);
    #pragma unroll
    for (int j=0;j<8;++j){ float f=b2f((u16)v[j]); s[j]+=f; ss[j]+=f*f; }
  }
  #pragma unroll
  for (int j=0;j<8;++j) red[rg*C + cu*8 + j] = s[j];
  __syncthreads();
  for (int c=threadIdx.x; c<C; c+=256){
    float t=0.f;
    #pragma unroll
    for (int r2=0;r2<NR;++r2) t += red[r2*C+c];
    stats[blockIdx.x*512 + c] = t;
  }
  __syncthreads();
  #pragma unroll
  for (int j=0;j<8;++j) red[rg*C + cu*8 + j] = ss[j];
  __syncthreads();
  for (int c=threadIdx.x; c<C; c+=256){
    float t=0.f;
    #pragma unroll
    for (int r2=0;r2<NR;++r2) t += red[r2*C+c];
    stats[131072 + blockIdx.x*512 + c] = t;
  }
}

template<int C>
__global__ __launch_bounds__(C) void bn_finalize(float* __restrict__ stats, const float* __restrict__ g,
                                                 const float* __restrict__ be, float cnt){
  int c = threadIdx.x;
  float s=0.f, ss=0.f;
  for (int b=0;b<256;++b){ s += stats[b*512+c]; ss += stats[131072 + b*512+c]; }
  float m = s/cnt;
  float var = ss/cnt - m*m;
  float A = rsqrtf(var + 1e-5f)*g[c];
  stats[262144 + c] = A;
  stats[262144 + 512 + c] = be[c] - m*A;
}

template<int C, int OH>
__global__ __launch_bounds__(256) void bn_apply(const u16* __restrict__ y, const float* __restrict__ stats,
                                                u16* __restrict__ xp){
  constexpr int S = OH*OH, LS = ilog2c(S), LOW = ilog2c(OH);
  constexpr int CU = C/8, LCU = ilog2c(CU);
  int idx = blockIdx.x*256 + threadIdx.x;
  int p = idx >> LCU, cu = idx & (CU-1);
  short8 v8 = *(const short8*)(y + (size_t)p*C + cu*8);
  const float* Ap = stats + 262144;
  const float* Bp = stats + 262144 + 512;
  u16 o[8];
  #pragma unroll
  for (int j=0;j<8;++j){
    float v = b2f((u16)v8[j])*Ap[cu*8+j] + Bp[cu*8+j];
    o[j] = f2b(v>=0.f ? v : 0.2f*v);
  }
  int b = p>>LS, s = p&(S-1), oh = s>>LOW, ow = s&(OH-1);
  *(short8*)(xp + ((size_t)(b*(OH+2)+oh+1)*(OH+2)+ow+1)*C + cu*8) = *(short8*)o;
}

__global__ __launch_bounds__(256) void mbd_kernel(
    const float* __restrict__ Ms, float* __restrict__ out)
{
  const int i = blockIdx.x;
  const int o = threadIdx.x;
  float mi[16];
  #pragma unroll
  for (int u = 0; u < 4; ++u) {
    float4 v = *(const float4*)&Ms[(size_t)i * 4096 + o * 16 + u * 4];
    mi[u*4+0]=v.x; mi[u*4+1]=v.y; mi[u*4+2]=v.z; mi[u*4+3]=v.w;
  }
  float acc = 0.f;
  for (int j = 0; j < BB; ++j) {
    float d = 0.f;
    #pragma unroll
    for (int u = 0; u < 4; ++u) {
      float4 v = *(const float4*)&Ms[(size_t)j * 4096 + o * 16 + u * 4];
      d += fabsf(mi[u*4+0]-v.x) + fabsf(mi[u*4+1]-v.y) + fabsf(mi[u*4+2]-v.z) + fabsf(mi[u*4+3]-v.w);
    }
    acc += expf(-d);
  }
  out[(size_t)i * 1280 + 1024 + o] = acc;
}

__global__ void ws_too_small(float* out, int n){
  int idx = blockIdx.x*256+threadIdx.x;
  if (idx<n) out[idx] = -777.0f;
}

extern "C" void kernel_launch(void* const* d_in, const int* in_sizes, int n_in,
                              void* d_out, int out_size, void* d_ws, size_t ws_size,
                              hipStream_t stream)
{
  const float* image = (const float*)d_in[0];
  const float* wvec  = (const float*)d_in[1];
  const float* fc_w  = (const float*)d_in[2];
  const float* w1    = (const float*)d_in[3];
  const float* w2    = (const float*)d_in[4];
  const float* w3    = (const float*)d_in[5];
  const float* w4    = (const float*)d_in[6];
  const float* w5    = (const float*)d_in[7];
  const float* g2    = (const float*)d_in[8];
  const float* b2    = (const float*)d_in[9];
  const float* g3    = (const float*)d_in[10];
  const float* b3    = (const float*)d_in[11];
  const float* g4    = (const float*)d_in[12];
  const float* b4    = (const float*)d_in[13];
  const float* T     = (const float*)d_in[14];
  float* out = (float*)d_out;
  char* wsb = (char*)d_ws;

  const size_t NEED = 105816064ull;
  if (ws_size < NEED) {
    ws_too_small<<<(out_size + 255)/256, 256, 0, stream>>>(out, out_size);
    return;
  }

  u16* xp1   = (u16*)(wsb + 0);
  u16* y3    = (u16*)(wsb + 0);
  u16* xp3   = (u16*)(wsb + 4194304);
  u16* y4    = (u16*)(wsb + 10747904);
  u16* xp4   = (u16*)(wsb + 12845056);
  float* Ms  = (float*)(wsb + 17563648);
  u16* featb = (u16*)(wsb + 19660800);
  float* stats = (float*)(wsb + 19922944);
  u16* xp2   = (u16*)(wsb + 37879808);
  float* c4part = (float*)(wsb + 37879808);    // reuses xp2 region (dead after conv3): 16 MB
  float* c5part = (float*)(wsb + 37879808);    // 4 MB, after conv4 reduce consumed
  u16* y2    = (u16*)(wsb + 59113472);
  float* gpart  = (float*)(wsb + 59113472);    // y2 region: 16,777,216 B
  float* c3part = (float*)(wsb + 59113472);    // conv3 partials [2][8192][256] fp32 = 16 MB
  u16* xp0   = (u16*)(wsb + 75890688);
  u16* wt1T  = (u16*)(wsb + 84811776);
  u16* wt2T  = (u16*)(wsb + 84844544);
  u16* wt3T  = (u16*)(wsb + 85893120);
  u16* wt4T  = (u16*)(wsb + 87990272);
  u16* wt5T  = (u16*)(wsb + 92184576);
  u16* Tt    = (u16*)(wsb + 96378880);
  u16* wvb   = (u16*)(wsb + 104767488);

  // zero padded buffers (borders)
  hipMemsetAsync(xp0, 0, 8921088, stream);
  hipMemsetAsync(xp1, 0, 37879808, stream);
  hipMemsetAsync(xp2, 0, 21233664, stream);

  // repacks
  wvb_convert<<<2048, 256, 0, stream>>>(wvec, wvb);
  repack_w<4,8><<<128, 256, 0, stream>>>(w1, wt1T);
  repack_w<128,128><<<256, 256, 0, stream>>>(w2, wt2T);
  repack_w<256,256><<<256, 256, 0, stream>>>(w3, wt3T);
  repack_w<256,256><<<512, 256, 0, stream>>>(w4, wt4T);
  repack_w<512,512><<<256, 256, 0, stream>>>(w5, wt5T);
  transpose_T<<<dim3(128,32), 256, 0, stream>>>(T, Tt);

  // FC (K-split 8 x 512) -> partials -> relu-reduce into xp0 ch3
  gemm128_split<1><<<dim3(64,8), 256, 0, stream>>>(wvb, fc_w, gpart, 4096, 512);
  reduce_split<8,0><<<2048, 256, 0, stream>>>(gpart, xp0);
  pack_x0<<<2048, 256, 0, stream>>>(image, xp0);

  // conv1 + lrelu -> xp1 (128x128 tile, M=131072, N=128)
  convmm2<8,128,32,1><<<dim3(1,1024), 256, 0, stream>>>(xp0, wt1T, xp1);
  // conv2 -> y2 (M=32768, N=256)
  convmm2<128,256,16,0><<<dim3(2,256), 256, 0, stream>>>(xp1, wt2T, y2);

  // xp1 region dead: zero xp3/xp4 borders
  hipMemsetAsync(xp3, 0, 6553600, stream);
  hipMemsetAsync(xp4, 0, 4718592, stream);

  // BN2 + lrelu -> xp2
  bn_stats2<256><<<256, 256, 0, stream>>>(y2, stats, 128);
  bn_finalize<256><<<1, 256, 0, stream>>>(stats, g2, b2, 32768.f);
  bn_apply<256,16><<<4096, 256, 0, stream>>>(y2, stats, xp2);

  // conv3 (KSPLIT=2) -> partials in y2 region (dead) -> y3; BN3 -> xp3
  convmm2<256,256,8,3,2><<<dim3(2,64,2), 256, 0, stream>>>(xp2, wt3T, c3part);
  reduce_part<2><<<2048, 256, 0, stream>>>(c3part, y3, 524288);
  bn_stats2<256><<<256, 256, 0, stream>>>(y3, stats, 32);
  bn_finalize<256><<<1, 256, 0, stream>>>(stats, g3, b3, 8192.f);
  bn_apply<256,8><<<1024, 256, 0, stream>>>(y3, stats, xp3);

  // conv4 (KSPLIT=4) -> partials in xp2 region (dead) -> y4; BN4 -> xp4
  convmm2<256,512,4,3,4><<<dim3(4,16,4), 256, 0, stream>>>(xp3, wt4T, c4part);
  reduce_part<4><<<1024, 256, 0, stream>>>(c4part, y4, 262144);
  bn_stats2<512><<<256, 256, 0, stream>>>(y4, stats, 8);
  bn_finalize<512><<<1, 512, 0, stream>>>(stats, g4, b4, 2048.f);
  bn_apply<512,4><<<512, 256, 0, stream>>>(y4, stats, xp4);

  // conv5 (K-split 8, 64x64 tile) -> partials -> out feat + featb
  convmm<512,256,2,3,8><<<dim3(4,8,8), 256, 0, stream>>>(xp4, wt5T, c5part);
  conv5_reduce<<<512, 256, 0, stream>>>(c5part, out, featb);

  // Ms = feat @ T (K-split 8 x 128) -> partials in y2 region (dead) -> Ms fp32
  gemm128_split<0><<<dim3(64,8), 256, 0, stream>>>(featb, Tt, gpart, 1024, 128);
  reduce_split<8,1><<<2048, 256, 0, stream>>>(gpart, Ms);
  mbd_kernel<<<128, 256, 0, stream>>>(Ms, out);
}

// Round 5
// 295.432 us; speedup vs baseline: 45.4589x; 1.2072x over previous
//
#include <hip/hip_runtime.h>
#include <cstddef>

#define BB 128

typedef unsigned short u16;
typedef __attribute__((ext_vector_type(8))) short short8;
typedef __attribute__((ext_vector_type(4))) short short4v;
typedef __attribute__((ext_vector_type(4))) float f32x4;

constexpr int ilog2c(int v){ return v<=1 ? 0 : 1+ilog2c(v>>1); }

__device__ __forceinline__ u16 f2b(float f){
  union {float f; unsigned u;} x; x.f = f;
  unsigned u = x.u + 0x7fffu + ((x.u>>16)&1u);
  return (u16)(u>>16);
}
__device__ __forceinline__ float b2f(u16 h){
  union {unsigned u; float f;} x; x.u = ((unsigned)h)<<16;
  return x.f;
}

#define GLOAD_LDS16(gsrc, ldsdst) \
  __builtin_amdgcn_global_load_lds((const __attribute__((address_space(1))) void*)(gsrc), \
      (__attribute__((address_space(3))) void*)(ldsdst), 16, 0, 0)

// ============ implicit-GEMM conv: 128x128 tile, 512 threads (8 waves), gload_lds ============
// y[p][oc] = sum_k A[p][k] * wtT[oc][k],  k = (kh*4+kw)*IC + ic
// STORE: 0 = bf16 [M][OC]; 1 = lrelu -> padded bf16; 3 = fp32 partial [KSPLIT][M][OC]
template<int IC, int OC, int OH, int STORE, int KSPLIT=1>
__global__ __launch_bounds__(512) void convmm2(
    const u16* __restrict__ xp, const u16* __restrict__ wtT, void* __restrict__ yv)
{
  constexpr int OW = OH, S = OH*OW;
  constexpr int IHp = 2*OH+2, IWp = 2*OW+2;
  constexpr int KT = 16*IC;
  constexpr int KTS = KT / KSPLIT;
  constexpr int M = BB * S;
  constexpr int LS = ilog2c(S), LOW = ilog2c(OW), L4 = ilog2c(4*IC);
  __shared__ u16 As[128*64];
  __shared__ u16 Bs[128*64];
  const int tid = threadIdx.x;
  const int n0 = blockIdx.x*128;
  const int m0 = blockIdx.y*128;
  const int kbase = (KSPLIT>1) ? blockIdx.z*KTS : 0;
  const int wave = tid>>6, l = tid&63;
  const int wm = wave>>1, wn = wave&1;   // 4 x 2 wave grid; wave tile = 32M x 64N

  // staging constants: unit = tid + t*512 -> (row r, lds slot us); source slot au = us^(r&7)
  size_t abase[2]; int au[2];
  #pragma unroll
  for (int t=0;t<2;++t){
    int unit = tid + t*512;
    int r = unit>>3, us = unit&7;
    au[t] = us ^ (r&7);
    int p = m0 + r;
    int b = p >> LS, s = p & (S-1);
    int oh = s >> LOW, ow = s & (OW-1);
    abase[t] = ((size_t)(b*IHp + 2*oh)*IWp + 2*ow)*IC;
  }
  const u16* bsrc[2];
  #pragma unroll
  for (int t=0;t<2;++t){
    int unit = tid + t*512;
    int r = unit>>3, us = unit&7;
    bsrc[t] = wtT + (size_t)(n0+r)*KT + (size_t)(us ^ (r&7))*8;
  }

  f32x4 acc[2][4] = {};

  for (int k0=kbase; k0<kbase+KTS; k0+=64){
    #pragma unroll
    for (int t=0;t<2;++t){
      int k = k0 + au[t]*8;
      int kh = k >> L4, koff = k & (4*IC-1);
      GLOAD_LDS16(xp + abase[t] + (size_t)kh*IWp*IC + koff, &As[(size_t)(t*512 + wave*64)*8]);
    }
    #pragma unroll
    for (int t=0;t<2;++t){
      GLOAD_LDS16(bsrc[t] + k0, &Bs[(size_t)(t*512 + wave*64)*8]);
    }
    __syncthreads();
    #pragma unroll
    for (int kk=0;kk<2;++kk){
      short8 af[2], bfm[4];
      #pragma unroll
      for (int mi=0;mi<2;++mi){
        int row = wm*32 + mi*16 + (l&15);
        int u = (kk*4 + (l>>4)) ^ (row&7);
        af[mi] = *(const short8*)(&As[row*64 + u*8]);
      }
      #pragma unroll
      for (int ni=0;ni<4;++ni){
        int row = wn*64 + ni*16 + (l&15);
        int u = (kk*4 + (l>>4)) ^ (row&7);
        bfm[ni] = *(const short8*)(&Bs[row*64 + u*8]);
      }
      #pragma unroll
      for (int mi=0;mi<2;++mi)
        #pragma unroll
        for (int ni=0;ni<4;++ni)
          acc[mi][ni] = __builtin_amdgcn_mfma_f32_16x16x32_bf16(af[mi], bfm[ni], acc[mi][ni], 0,0,0);
    }
    __syncthreads();
  }
  #pragma unroll
  for (int mi=0;mi<2;++mi){
    #pragma unroll
    for (int ni=0;ni<4;++ni){
      #pragma unroll
      for (int r=0;r<4;++r){
        int row = m0 + wm*32 + mi*16 + (l>>4)*4 + r;
        int col = n0 + wn*64 + ni*16 + (l&15);
        float v = acc[mi][ni][r];
        if (STORE==0){
          ((u16*)yv)[(size_t)row*OC + col] = f2b(v);
        } else if (STORE==1){
          v = v>=0.f ? v : 0.2f*v;
          int b = row>>LS, s = row&(S-1);
          int oh = s>>LOW, ow = s&(OW-1);
          ((u16*)yv)[((size_t)(b*(OH+2) + oh+1)*(OW+2) + ow+1)*OC + col] = f2b(v);
        } else {
          ((float*)yv)[((size_t)blockIdx.z*M + row)*OC + col] = v;
        }
      }
    }
  }
}

// ============ K-split GEMM, M=128 fixed, N=4096 ============
template<int B_FP32>
__global__ __launch_bounds__(256) void gemm128_split(
    const u16* __restrict__ A, const void* __restrict__ Bsrc,
    float* __restrict__ part, int K, int kchunk)
{
  __shared__ u16 As[128*64];
  __shared__ u16 Bs[64*64];
  const int tid = threadIdx.x;
  const int n0 = blockIdx.x*64;
  const int kbase = blockIdx.y*kchunk;
  const int wv = tid>>6, l = tid&63;
  f32x4 acc[2][4] = {};
  for (int k0=kbase; k0<kbase+kchunk; k0+=64){
    #pragma unroll
    for (int t=0;t<4;++t){
      int unit = tid + t*256;
      int r = unit>>3, us = unit&7;
      int u = us ^ (r&7);
      *(float4*)(&As[r*64+us*8]) = *(const float4*)(A + (size_t)r*K + k0 + u*8);
    }
    if (B_FP32){
      const float* Bf = (const float*)Bsrc;
      #pragma unroll
      for (int t=0;t<4;++t){
        int unit = tid + t*256;
        int r = unit>>4, u4 = unit&15;
        int u = u4>>1, half = u4&1;
        int us = u ^ (r&7);
        float4 v = *(const float4*)(Bf + (size_t)(n0+r)*K + k0 + u4*4);
        short4v o; o[0]=(short)f2b(v.x); o[1]=(short)f2b(v.y); o[2]=(short)f2b(v.z); o[3]=(short)f2b(v.w);
        *(short4v*)(&Bs[r*64 + us*8 + half*4]) = o;
      }
    } else {
      const u16* Bb = (const u16*)Bsrc;
      #pragma unroll
      for (int t=0;t<2;++t){
        int unit = tid + t*256;
        int r = unit>>3, us = unit&7;
        int u = us ^ (r&7);
        *(float4*)(&Bs[r*64+us*8]) = *(const float4*)(Bb + (size_t)(n0+r)*K + k0 + u*8);
      }
    }
    __syncthreads();
    #pragma unroll
    for (int kk=0;kk<2;++kk){
      short8 af[2], bfm[4];
      #pragma unroll
      for (int mi=0;mi<2;++mi){
        int row = wv*32 + mi*16 + (l&15);
        int u = (kk*4 + (l>>4)) ^ (row&7);
        af[mi] = *(const short8*)(&As[row*64 + u*8]);
      }
      #pragma unroll
      for (int ni=0;ni<4;++ni){
        int row = ni*16 + (l&15);
        int u = (kk*4 + (l>>4)) ^ (row&7);
        bfm[ni] = *(const short8*)(&Bs[row*64 + u*8]);
      }
      #pragma unroll
      for (int mi=0;mi<2;++mi)
        #pragma unroll
        for (int ni=0;ni<4;++ni)
          acc[mi][ni] = __builtin_amdgcn_mfma_f32_16x16x32_bf16(af[mi], bfm[ni], acc[mi][ni], 0,0,0);
    }
    __syncthreads();
  }
  #pragma unroll
  for (int mi=0;mi<2;++mi){
    #pragma unroll
    for (int ni=0;ni<4;++ni){
      #pragma unroll
      for (int r=0;r<4;++r){
        int m = wv*32 + mi*16 + (l>>4)*4 + r;
        int n = n0 + ni*16 + (l&15);
        part[((size_t)blockIdx.y*128 + m)*4096 + n] = acc[mi][ni][r];
      }
    }
  }
}

// reduce NS partials of [128][4096]; STORE 0: relu -> xp0 ch3 ; 1: fp32 -> Ms
template<int NS, int STORE>
__global__ __launch_bounds__(256) void reduce_split(const float* __restrict__ part, void* __restrict__ outv)
{
  int idx = blockIdx.x*256 + threadIdx.x;
  float s = 0.f;
  #pragma unroll
  for (int i=0;i<NS;++i) s += part[(size_t)i*524288 + idx];
  if (STORE==0){
    float v = fmaxf(s, 0.f);
    int m = idx>>12, n = idx&4095;
    int h = n>>6, w2 = n&63;
    ((u16*)outv)[((size_t)(m*66 + h+1)*66 + w2+1)*8 + 3] = f2b(v);
  } else {
    ((float*)outv)[idx] = s;
  }
}

// reduce NS fp32 partials (vectorized x4) -> bf16
template<int NS>
__global__ __launch_bounds__(256) void reduce_part(const float* __restrict__ part,
                                                   u16* __restrict__ out, int total4)
{
  int idx = blockIdx.x*256 + threadIdx.x;
  float4 s = {0.f,0.f,0.f,0.f};
  #pragma unroll
  for (int i=0;i<NS;++i){
    float4 v = *(const float4*)(part + ((size_t)i*total4 + idx)*4);
    s.x+=v.x; s.y+=v.y; s.z+=v.z; s.w+=v.w;
  }
  short4v o; o[0]=(short)f2b(s.x); o[1]=(short)f2b(s.y); o[2]=(short)f2b(s.z); o[3]=(short)f2b(s.w);
  *(short4v*)(out + (size_t)idx*4) = o;
}

// reduce conv5 partials [32][512][256] -> d_out feat (permuted fp32) + featb (bf16 [128][1024])
__global__ __launch_bounds__(256) void conv5_reduce(const float* __restrict__ part,
                                                    float* __restrict__ out, u16* __restrict__ featb)
{
  int idx = blockIdx.x*256 + threadIdx.x;   // 131072
  float s = 0.f;
  #pragma unroll
  for (int i=0;i<32;++i) s += part[(size_t)i*131072 + idx];
  int row = idx>>8, col = idx&255;
  int b = row>>2, sp = row&3;
  out[(size_t)b*1280 + col*4 + sp] = s;
  featb[(size_t)b*1024 + col*4 + sp] = f2b(s);
}

// ============ fused prologue: weight repacks + T transpose + wv convert ============
template<int IC, int ICP>
__device__ __forceinline__ void repack_dev(const float* __restrict__ w, u16* __restrict__ wt,
                                           int oc, int tid, float* ls){
  for (int i=tid; i<IC*16; i+=256){
    int ic = i>>4, khkw = i&15;
    ls[ic*17+khkw] = w[(size_t)oc*IC*16 + i];
  }
  __syncthreads();
  constexpr int KT = 16*ICP;
  constexpr int LP = ilog2c(ICP);
  for (int k=tid; k<KT; k+=256){
    int khkw = k >> LP, ic = k & (ICP-1);
    float v = (ic<IC) ? ls[ic*17+khkw] : 0.f;
    wt[(size_t)oc*KT + k] = f2b(v);
  }
}

__device__ __forceinline__ void transpose_dev(const float* __restrict__ T, u16* __restrict__ Tt,
                                              int idx, int tid, float* tile){
  int bx = idx & 127, by = idx >> 7;
  int kb = by*32, nb = bx*32;
  int tx = tid&31, ty = tid>>5;
  #pragma unroll
  for (int i=0;i<32;i+=8)
    tile[(ty+i)*33 + tx] = T[(size_t)(kb+ty+i)*4096 + nb+tx];
  __syncthreads();
  #pragma unroll
  for (int i=0;i<32;i+=8)
    Tt[(size_t)(nb+ty+i)*1024 + kb+tx] = f2b(tile[tx*33 + ty+i]);
}

__global__ __launch_bounds__(256) void prep_all(
    const float* __restrict__ w1, const float* __restrict__ w2, const float* __restrict__ w3,
    const float* __restrict__ w4, const float* __restrict__ w5, const float* __restrict__ T,
    const float* __restrict__ wvec,
    u16* wt1T, u16* wt2T, u16* wt3T, u16* wt4T, u16* wt5T, u16* Tt, u16* wvb)
{
  __shared__ float ls[512*17];
  const int blk = blockIdx.x, tid = threadIdx.x;
  if (blk < 128)        repack_dev<4,8>(w1, wt1T, blk, tid, ls);
  else if (blk < 384)   repack_dev<128,128>(w2, wt2T, blk-128, tid, ls);
  else if (blk < 640)   repack_dev<256,256>(w3, wt3T, blk-384, tid, ls);
  else if (blk < 1152)  repack_dev<256,256>(w4, wt4T, blk-640, tid, ls);
  else if (blk < 1408)  repack_dev<512,512>(w5, wt5T, blk-1152, tid, ls);
  else if (blk < 5504)  transpose_dev(T, Tt, blk-1408, tid, ls);
  else { int i = (blk-5504)*256 + tid; wvb[i] = f2b(wvec[i]); }
}

// ============ border zeroing (replaces full-buffer memsets) ============
template<int Hp, int C>
__device__ __forceinline__ void zb_border(u16* __restrict__ buf, int idx, int count){
  if (idx >= count) return;
  constexpr int NP = 4*Hp - 4;
  constexpr int PC = NP*C;
  int b = idx / PC;
  int rem = idx - b*PC;
  int p = rem >> ilog2c(C);
  int c = rem & (C-1);
  int h, w;
  if (p < Hp){ h = 0; w = p; }
  else if (p < 2*Hp){ h = Hp-1; w = p - Hp; }
  else { int q = p - 2*Hp; h = 1 + (q>>1); w = (q&1) ? (Hp-1) : 0; }
  buf[(((size_t)b*Hp + h)*Hp + w)*C + c] = 0;
}

// xp0 fully zeroed (ch 4..7 never rewritten); xp1/xp2 borders only
__global__ __launch_bounds__(256) void zb_early(u16* xp0, u16* xp1, u16* xp2){
  const int blk = blockIdx.x, tid = threadIdx.x;
  if (blk < 2178){
    int i = blk*256 + tid;            // 557568 short8 units = 4,460,544 u16
    if (i < 557568){ short8 z = {}; *(short8*)(xp0 + (size_t)i*8) = z; }
  } else if (blk < 10626){
    zb_border<34,128>(xp1, (blk-2178)*256 + tid, 2162688);
  } else {
    zb_border<18,256>(xp2, (blk-10626)*256 + tid, 2228224);
  }
}

// xp3/xp4 alias the xp1 region -> must zero after conv2 consumed xp1
__global__ __launch_bounds__(256) void zb_late(u16* xp3, u16* xp4){
  const int blk = blockIdx.x, tid = threadIdx.x;
  if (blk < 4608) zb_border<10,256>(xp3, blk*256 + tid, 1179648);
  else            zb_border<6,512>(xp4, (blk-4608)*256 + tid, 1310720);
}

// ============ support kernels ============
__global__ __launch_bounds__(256) void pack_x0(const float* __restrict__ img, u16* __restrict__ xp0){
  int idx = blockIdx.x*256+threadIdx.x;   // b*4096+s
  int b = idx>>12, s = idx&4095;
  int h = s>>6, w = s&63;
  u16* d = xp0 + ((size_t)(b*66 + h+1)*66 + w+1)*8;
  d[0] = f2b(img[(size_t)(b*3+0)*4096 + s]);
  d[1] = f2b(img[(size_t)(b*3+1)*4096 + s]);
  d[2] = f2b(img[(size_t)(b*3+2)*4096 + s]);
}

// deterministic two-stage BN stats, coalesced short8 loads
template<int C>
__global__ __launch_bounds__(256) void bn_stats2(const u16* __restrict__ y, float* __restrict__ stats, int Mblk){
  constexpr int CU = C/8, NR = 256/CU, LCU = ilog2c(CU);
  __shared__ float red[NR*C];
  const int cu = threadIdx.x & (CU-1);
  const int rg = threadIdx.x >> LCU;
  const int base = blockIdx.x*Mblk;
  float s[8] = {}, ss[8] = {};
  for (int p = base+rg; p < base+Mblk; p += NR){
    short8 v = *(const short8*)(y + (size_t)p*C + cu*8);
    #pragma unroll
    for (int j=0;j<8;++j){ float f=b2f((u16)v[j]); s[j]+=f; ss[j]+=f*f; }
  }
  #pragma unroll
  for (int j=0;j<8;++j) red[rg*C + cu*8 + j] = s[j];
  __syncthreads();
  for (int c=threadIdx.x; c<C; c+=256){
    float t=0.f;
    #pragma unroll
    for (int r2=0;r2<NR;++r2) t += red[r2*C+c];
    stats[blockIdx.x*512 + c] = t;
  }
  __syncthreads();
  #pragma unroll
  for (int j=0;j<8;++j) red[rg*C + cu*8 + j] = ss[j];
  __syncthreads();
  for (int c=threadIdx.x; c<C; c+=256){
    float t=0.f;
    #pragma unroll
    for (int r2=0;r2<NR;++r2) t += red[r2*C+c];
    stats[131072 + blockIdx.x*512 + c] = t;
  }
}

template<int C>
__global__ __launch_bounds__(C) void bn_finalize(float* __restrict__ stats, const float* __restrict__ g,
                                                 const float* __restrict__ be, float cnt){
  int c = threadIdx.x;
  float s=0.f, ss=0.f;
  for (int b=0;b<256;++b){ s += stats[b*512+c]; ss += stats[131072 + b*512+c]; }
  float m = s/cnt;
  float var = ss/cnt - m*m;
  float A = rsqrtf(var + 1e-5f)*g[c];
  stats[262144 + c] = A;
  stats[262144 + 512 + c] = be[c] - m*A;
}

template<int C, int OH>
__global__ __launch_bounds__(256) void bn_apply(const u16* __restrict__ y, const float* __restrict__ stats,
                                                u16* __restrict__ xp){
  constexpr int S = OH*OH, LS = ilog2c(S), LOW = ilog2c(OH);
  constexpr int CU = C/8, LCU = ilog2c(CU);
  int idx = blockIdx.x*256 + threadIdx.x;
  int p = idx >> LCU, cu = idx & (CU-1);
  short8 v8 = *(const short8*)(y + (size_t)p*C + cu*8);
  const float* Ap = stats + 262144;
  const float* Bp = stats + 262144 + 512;
  u16 o[8];
  #pragma unroll
  for (int j=0;j<8;++j){
    float v = b2f((u16)v8[j])*Ap[cu*8+j] + Bp[cu*8+j];
    o[j] = f2b(v>=0.f ? v : 0.2f*v);
  }
  int b = p>>LS, s = p&(S-1), oh = s>>LOW, ow = s&(OH-1);
  *(short8*)(xp + ((size_t)(b*(OH+2)+oh+1)*(OH+2)+ow+1)*C + cu*8) = *(short8*)o;
}

__global__ __launch_bounds__(256) void mbd_kernel(
    const float* __restrict__ Ms, float* __restrict__ out)
{
  const int i = blockIdx.x;
  const int o = threadIdx.x;
  float mi[16];
  #pragma unroll
  for (int u = 0; u < 4; ++u) {
    float4 v = *(const float4*)&Ms[(size_t)i * 4096 + o * 16 + u * 4];
    mi[u*4+0]=v.x; mi[u*4+1]=v.y; mi[u*4+2]=v.z; mi[u*4+3]=v.w;
  }
  float acc = 0.f;
  for (int j = 0; j < BB; ++j) {
    float d = 0.f;
    #pragma unroll
    for (int u = 0; u < 4; ++u) {
      float4 v = *(const float4*)&Ms[(size_t)j * 4096 + o * 16 + u * 4];
      d += fabsf(mi[u*4+0]-v.x) + fabsf(mi[u*4+1]-v.y) + fabsf(mi[u*4+2]-v.z) + fabsf(mi[u*4+3]-v.w);
    }
    acc += expf(-d);
  }
  out[(size_t)i * 1280 + 1024 + o] = acc;
}

__global__ void ws_too_small(float* out, int n){
  int idx = blockIdx.x*256+threadIdx.x;
  if (idx<n) out[idx] = -777.0f;
}

extern "C" void kernel_launch(void* const* d_in, const int* in_sizes, int n_in,
                              void* d_out, int out_size, void* d_ws, size_t ws_size,
                              hipStream_t stream)
{
  const float* image = (const float*)d_in[0];
  const float* wvec  = (const float*)d_in[1];
  const float* fc_w  = (const float*)d_in[2];
  const float* w1    = (const float*)d_in[3];
  const float* w2    = (const float*)d_in[4];
  const float* w3    = (const float*)d_in[5];
  const float* w4    = (const float*)d_in[6];
  const float* w5    = (const float*)d_in[7];
  const float* g2    = (const float*)d_in[8];
  const float* b2    = (const float*)d_in[9];
  const float* g3    = (const float*)d_in[10];
  const float* b3    = (const float*)d_in[11];
  const float* g4    = (const float*)d_in[12];
  const float* b4    = (const float*)d_in[13];
  const float* T     = (const float*)d_in[14];
  float* out = (float*)d_out;
  char* wsb = (char*)d_ws;

  const size_t NEED = 105816064ull;
  if (ws_size < NEED) {
    ws_too_small<<<(out_size + 255)/256, 256, 0, stream>>>(out, out_size);
    return;
  }

  u16* xp1   = (u16*)(wsb + 0);
  u16* y3    = (u16*)(wsb + 0);
  u16* xp3   = (u16*)(wsb + 4194304);
  u16* y4    = (u16*)(wsb + 10747904);
  u16* xp4   = (u16*)(wsb + 12845056);
  float* Ms  = (float*)(wsb + 17563648);
  u16* featb = (u16*)(wsb + 19660800);
  float* stats = (float*)(wsb + 19922944);
  u16* xp2   = (u16*)(wsb + 37879808);
  float* c4part = (float*)(wsb + 37879808);    // xp2 region reuse (dead after conv3)
  float* c5part = (float*)(wsb + 37879808);    // [32][512][256] fp32 = 16.8 MB
  u16* y2    = (u16*)(wsb + 59113472);
  float* gpart  = (float*)(wsb + 59113472);    // y2 region: 16,777,216 B
  float* c3part = (float*)(wsb + 59113472);
  u16* xp0   = (u16*)(wsb + 75890688);
  u16* wt1T  = (u16*)(wsb + 84811776);
  u16* wt2T  = (u16*)(wsb + 84844544);
  u16* wt3T  = (u16*)(wsb + 85893120);
  u16* wt4T  = (u16*)(wsb + 87990272);
  u16* wt5T  = (u16*)(wsb + 92184576);
  u16* Tt    = (u16*)(wsb + 96378880);
  u16* wvb   = (u16*)(wsb + 104767488);

  // zero xp0 (full) + xp1/xp2 borders; fused weight prep
  zb_early<<<19330, 256, 0, stream>>>(xp0, xp1, xp2);
  prep_all<<<7552, 256, 0, stream>>>(w1, w2, w3, w4, w5, T, wvec,
                                     wt1T, wt2T, wt3T, wt4T, wt5T, Tt, wvb);

  // FC (K-split 8 x 512) -> partials -> relu-reduce into xp0 ch3
  gemm128_split<1><<<dim3(64,8), 256, 0, stream>>>(wvb, fc_w, gpart, 4096, 512);
  reduce_split<8,0><<<2048, 256, 0, stream>>>(gpart, xp0);
  pack_x0<<<2048, 256, 0, stream>>>(image, xp0);

  // conv1 + lrelu -> xp1 (M=131072, N=128)
  convmm2<8,128,32,1><<<dim3(1,1024), 512, 0, stream>>>(xp0, wt1T, xp1);
  // conv2 -> y2 (M=32768, N=256, K=2048)
  convmm2<128,256,16,0><<<dim3(2,256), 512, 0, stream>>>(xp1, wt2T, y2);

  // xp1 region dead: zero xp3/xp4 borders
  zb_late<<<9728, 256, 0, stream>>>(xp3, xp4);

  // BN2 + lrelu -> xp2
  bn_stats2<256><<<256, 256, 0, stream>>>(y2, stats, 128);
  bn_finalize<256><<<1, 256, 0, stream>>>(stats, g2, b2, 32768.f);
  bn_apply<256,16><<<4096, 256, 0, stream>>>(y2, stats, xp2);

  // conv3 (KSPLIT=2) -> partials -> y3; BN3 -> xp3
  convmm2<256,256,8,3,2><<<dim3(2,64,2), 512, 0, stream>>>(xp2, wt3T, c3part);
  reduce_part<2><<<2048, 256, 0, stream>>>(c3part, y3, 524288);
  bn_stats2<256><<<256, 256, 0, stream>>>(y3, stats, 32);
  bn_finalize<256><<<1, 256, 0, stream>>>(stats, g3, b3, 8192.f);
  bn_apply<256,8><<<1024, 256, 0, stream>>>(y3, stats, xp3);

  // conv4 (KSPLIT=4) -> partials -> y4; BN4 -> xp4
  convmm2<256,512,4,3,4><<<dim3(4,16,4), 512, 0, stream>>>(xp3, wt4T, c4part);
  reduce_part<4><<<1024, 256, 0, stream>>>(c4part, y4, 262144);
  bn_stats2<512><<<256, 256, 0, stream>>>(y4, stats, 8);
  bn_finalize<512><<<1, 512, 0, stream>>>(stats, g4, b4, 2048.f);
  bn_apply<512,4><<<512, 256, 0, stream>>>(y4, stats, xp4);

  // conv5 (M=512, N=256, K=8192, KSPLIT=32) -> partials -> out feat + featb
  convmm2<512,256,2,3,32><<<dim3(2,4,32), 512, 0, stream>>>(xp4, wt5T, c5part);
  conv5_reduce<<<512, 256, 0, stream>>>(c5part, out, featb);

  // Ms = feat @ T (K-split 8 x 128) -> partials -> Ms fp32
  gemm128_split<0><<<dim3(64,8), 256, 0, stream>>>(featb, Tt, gpart, 1024, 128);
  reduce_split<8,1><<<2048, 256, 0, stream>>>(gpart, Ms);
  mbd_kernel<<<128, 256, 0, stream>>>(Ms, out);
}